// Round 7
// baseline (184573.718 us; speedup 1.0000x reference)
//
#include <hip/hip_runtime.h>
#include <math.h>

#define DIM 512
#define BATCH 4096
#define NSTEPS 30
#define KEEP 321

#define S_BETA 0
#define S_SCALE 1
#define S_VTV 4
#define S_SC 5

#define TDG 32     // workgroups cooperating in k_tridiag_mw / k_chol_mw
#define NB 8       // tridiag panel width (deferred rank-2NB updates)
#define MTAIL 160  // tridiag: below this trailing size, WG0 finishes alone (no grid barriers)

__device__ __forceinline__ double wred(double v) {
#pragma unroll
  for (int o = 32; o > 0; o >>= 1) v += __shfl_down(v, (unsigned)o, 64);
  return v;
}

// Agent-scope (device) relaxed atomics: sc0|sc1 accesses that write-through / read-through
// the die-level coherence point. No L2 writeback/invalidate involved.
__device__ __forceinline__ void stg(double* p, double v) {
  __hip_atomic_store(p, v, __ATOMIC_RELAXED, __HIP_MEMORY_SCOPE_AGENT);
}
__device__ __forceinline__ double ldg_(const double* p) {
  return __hip_atomic_load(p, __ATOMIC_RELAXED, __HIP_MEMORY_SCOPE_AGENT);
}

// Heavyweight grid barrier (full agent fences) — ONLY where bulk L2-cached data must
// become visible across WGs (co-op -> tail handoff in tridiag).
__device__ __forceinline__ void gbar2(unsigned* __restrict__ flags, unsigned& gen) {
  gen++;
  const unsigned target = gen;
  __syncthreads();
  if (threadIdx.x == 0) {
    __threadfence();
    __hip_atomic_store(flags + (size_t)blockIdx.x * 32, target, __ATOMIC_RELAXED, __HIP_MEMORY_SCOPE_AGENT);
  }
  if (threadIdx.x < 64) {
    bool ok = ((int)threadIdx.x >= TDG);
    while (!__all(ok)) {
      if (!ok) {
        unsigned v = __hip_atomic_load(flags + (size_t)threadIdx.x * 32, __ATOMIC_RELAXED, __HIP_MEMORY_SCOPE_AGENT);
        ok = (v >= target);
      }
    }
    __threadfence();
  }
  __syncthreads();
}

// Fence-free grid barrier: all cross-WG data goes through stg/ldg_ (sc0sc1).
__device__ __forceinline__ void gbarf(unsigned* __restrict__ flags, unsigned& gen) {
  gen++;
  const unsigned target = gen;
  __syncthreads();
  if (threadIdx.x == 0) {
    __hip_atomic_store(flags + (size_t)blockIdx.x * 32, target, __ATOMIC_RELAXED, __HIP_MEMORY_SCOPE_AGENT);
  }
  if (threadIdx.x < 64) {
    bool ok = ((int)threadIdx.x >= TDG);
    while (!__all(ok)) {
      if (!ok) {
        unsigned v = __hip_atomic_load(flags + (size_t)threadIdx.x * 32, __ATOMIC_RELAXED, __HIP_MEMORY_SCOPE_AGENT);
        ok = (v >= target);
      }
    }
    asm volatile("" ::: "memory");
  }
  __syncthreads();
}

// ---------------- setup kernels ----------------

__global__ __launch_bounds__(256) void k_cast(const float* __restrict__ W, const float* __restrict__ b,
                                              double* __restrict__ Wd, double* __restrict__ bd,
                                              unsigned* __restrict__ cflags) {
  int idx = blockIdx.x * 256 + threadIdx.x;
  if (idx < DIM * DIM) Wd[idx] = (double)W[idx];
  if (idx < DIM) bd[idx] = (double)b[idx];
  if (blockIdx.x == 0) {
    for (int i = threadIdx.x; i < 1024; i += 256) cflags[i] = 0;
  }
}

__global__ __launch_bounds__(512) void k_colsum(const float* __restrict__ x, double* __restrict__ mvec) {
  int j = threadIdx.x;
  double s = 0.0;
  for (int r = 0; r < BATCH; ++r) s += (double)x[(size_t)r * DIM + j];
  mvec[j] = s;
}

// Gx = x^T x in fp64 (x fp32).
__global__ __launch_bounds__(256) void k_xtx(const float* __restrict__ x, double* __restrict__ Gx) {
  __shared__ double As[16][65];
  __shared__ double Bs[16][65];
  const int tid = threadIdx.x;
  const int tx = tid & 15, ty = tid >> 4;
  const int bi = blockIdx.y * 64, bj = blockIdx.x * 64;
  const int lr = tid >> 4, lc4 = (tid & 15) * 4;
  double acc[4][4] = {};
  for (int r0 = 0; r0 < BATCH; r0 += 16) {
#pragma unroll
    for (int q = 0; q < 4; ++q) {
      As[lr][lc4 + q] = (double)x[(size_t)(r0 + lr) * DIM + bi + lc4 + q];
      Bs[lr][lc4 + q] = (double)x[(size_t)(r0 + lr) * DIM + bj + lc4 + q];
    }
    __syncthreads();
#pragma unroll
    for (int rr = 0; rr < 16; ++rr) {
      double a[4], bb[4];
#pragma unroll
      for (int u = 0; u < 4; ++u) a[u] = As[rr][ty * 4 + u];
#pragma unroll
      for (int v = 0; v < 4; ++v) bb[v] = Bs[rr][tx * 4 + v];
#pragma unroll
      for (int u = 0; u < 4; ++u)
#pragma unroll
        for (int v = 0; v < 4; ++v) acc[u][v] += a[u] * bb[v];
    }
    __syncthreads();
  }
#pragma unroll
  for (int u = 0; u < 4; ++u)
#pragma unroll
    for (int v = 0; v < 4; ++v) Gx[(size_t)(bi + ty * 4 + u) * DIM + bj + tx * 4 + v] = acc[u][v];
}

// Multi-WG Cholesky Gx = R^T R (R upper, lower zeroed), TDG WGs.
__global__ __launch_bounds__(256) void k_chol_mw(const double* __restrict__ G, double* __restrict__ R,
                                                 unsigned* __restrict__ flags) {
  __shared__ double Lr[16][512];
  __shared__ double rowk[512];
  const int tid = threadIdx.x, lane = tid & 63, wid = tid >> 6;
  const int g = blockIdx.x;
  unsigned gen = 0;
  for (int s = 0; s < 16; ++s) {
    const int i = s * 32 + g;
    for (int j = tid; j < DIM; j += 256) Lr[s][j] = G[(size_t)i * DIM + j];
  }
  __syncthreads();
  for (int k = 0; k < DIM; ++k) {
    if ((k & 31) == g) {
      const int s = k >> 5;
      double dkk = Lr[s][k];
      double sq = sqrt(fmax(dkk, 1e-280));
      double inv = 1.0 / sq;
      for (int j = tid; j < DIM; j += 256) {
        double v;
        if (j < k) v = 0.0;
        else if (j == k) v = sq;
        else v = Lr[s][j] * inv;
        stg(&R[(size_t)k * DIM + j], v);
      }
    }
    gbarf(flags, gen);
    for (int j = k + tid; j < DIM; j += 256) rowk[j] = ldg_(&R[(size_t)k * DIM + j]);
    __syncthreads();
    for (int s = wid; s < 16; s += 4) {
      const int i = s * 32 + g;
      if (i <= k) continue;
      const double rki = rowk[i];
      for (int j = i + lane; j < DIM; j += 64) Lr[s][j] -= rki * rowk[j];
    }
    __syncthreads();
  }
}

// forward-substitution R^T c0 = mvec — single wave, rhs in registers, no barriers
__global__ __launch_bounds__(64) void k_solvec0(const double* __restrict__ R, const double* __restrict__ mvec,
                                                double* __restrict__ c0) {
  const int lane = threadIdx.x;
  double rhs[8], cs[8];
#pragma unroll
  for (int r = 0; r < 8; ++r) rhs[r] = mvec[lane + 64 * r];
#pragma unroll
  for (int r = 0; r < 8; ++r) cs[r] = 0.0;
  for (int i = 0; i < DIM; ++i) {
    int owner = i & 63, ri = i >> 6;
    double ci = 0.0;
    if (lane == owner) {
      ci = rhs[ri] / R[(size_t)i * DIM + i];
      cs[ri] = ci;
    }
    ci = __shfl(ci, owner, 64);
    const double* row = R + (size_t)i * DIM;
#pragma unroll
    for (int r = 0; r < 8; ++r) {
      int j = lane + 64 * r;
      if (j > i) rhs[r] -= ci * row[j];
    }
  }
#pragma unroll
  for (int r = 0; r < 8; ++r) c0[lane + 64 * r] = cs[r];
}

// ---------------- per-step kernels ----------------

__global__ __launch_bounds__(512) void k_prep(const double* __restrict__ cstv, const double* __restrict__ bd, int r,
                                              double* __restrict__ tvec, double* __restrict__ Mm,
                                              double* __restrict__ scal, unsigned* __restrict__ tflags) {
  __shared__ double redb[8];
  __shared__ double bc[1];
  const int tid = threadIdx.x, lane = tid & 63, wid = tid >> 6;
  for (int i = tid; i < 1024; i += 512) tflags[i] = 0;  // reset tridiag barrier flags
  double p = 0.0;
  for (int i = tid; i < r; i += 512) {
    double c = cstv[i];
    p += c * c;
    tvec[i] = c;
  }
  p = wred(p);
  if (lane == 0) redb[wid] = p;
  __syncthreads();
  if (tid == 0) {
    double s = 0;
    for (int q = 0; q < 8; ++q) s += redb[q];
    double beta = sqrt(fmax(4096.0 - s, 1e-20));
    tvec[r] = beta;
    scal[S_BETA] = beta;
    bc[0] = beta;
  }
  __syncthreads();
  double beta = bc[0];
  for (int j = tid; j < DIM; j += 512) Mm[(size_t)r * DIM + j] = beta * bd[j];
}

// C[MxN] = A·B^T (+ ur·vr^T), row-major, fp64.
__global__ __launch_bounds__(256) void k_gemm_nt(const double* __restrict__ A, const double* __restrict__ B,
                                                 double* __restrict__ C, int M, int N, int Kd, int lda, int ldb, int ldc,
                                                 const double* __restrict__ ur, const double* __restrict__ vr) {
  __shared__ double As[16][65];
  __shared__ double Bs[16][65];
  const int tid = threadIdx.x;
  const int tx = tid & 15, ty = tid >> 4;
  const int bi = blockIdx.y * 64, bj = blockIdx.x * 64;
  const int li = tid >> 2, lk = (tid & 3) * 4;
  double acc[4][4] = {};
  for (int k0 = 0; k0 < Kd; k0 += 16) {
    int gi = bi + li;
    bool oa = (gi < M);
    const double* pa = A + (size_t)(oa ? gi : 0) * lda + k0 + lk;
    int gj = bj + li;
    bool ob = (gj < N);
    const double* pb = B + (size_t)(ob ? gj : 0) * ldb + k0 + lk;
#pragma unroll
    for (int q = 0; q < 4; ++q) {
      int gk = k0 + lk + q;
      As[lk + q][li] = (oa && gk < Kd) ? pa[q] : 0.0;
      Bs[lk + q][li] = (ob && gk < Kd) ? pb[q] : 0.0;
    }
    __syncthreads();
#pragma unroll
    for (int kk = 0; kk < 16; ++kk) {
      double a[4], bb[4];
#pragma unroll
      for (int u = 0; u < 4; ++u) a[u] = As[kk][ty * 4 + u];
#pragma unroll
      for (int v = 0; v < 4; ++v) bb[v] = Bs[kk][tx * 4 + v];
#pragma unroll
      for (int u = 0; u < 4; ++u)
#pragma unroll
        for (int v = 0; v < 4; ++v) acc[u][v] += a[u] * bb[v];
    }
    __syncthreads();
  }
#pragma unroll
  for (int u = 0; u < 4; ++u) {
    int gi = bi + ty * 4 + u;
    if (gi >= M) continue;
#pragma unroll
    for (int v = 0; v < 4; ++v) {
      int gj = bj + tx * 4 + v;
      if (gj >= N) continue;
      double val = acc[u][v];
      if (ur) val += ur[gi] * vr[gj];
      C[(size_t)gi * ldc + gj] = val;
    }
  }
}

// C = M·M^T (symmetric): only lower-triangular block pairs, mirror write.
__global__ __launch_bounds__(256) void k_syrk(const double* __restrict__ M, double* __restrict__ C, int n, int Kd,
                                              int ld, int ldc) {
  __shared__ double As[16][65];
  __shared__ double Bs[16][65];
  int bid = blockIdx.x;
  int by = 0;
  while ((by + 1) * (by + 2) / 2 <= bid) by++;
  int bx = bid - by * (by + 1) / 2;
  const int tid = threadIdx.x;
  const int tx = tid & 15, ty = tid >> 4;
  const int bi = by * 64, bj = bx * 64;
  const int li = tid >> 2, lk = (tid & 3) * 4;
  double acc[4][4] = {};
  for (int k0 = 0; k0 < Kd; k0 += 16) {
    int gi = bi + li;
    bool oa = (gi < n);
    const double* pa = M + (size_t)(oa ? gi : 0) * ld + k0 + lk;
    int gj = bj + li;
    bool ob = (gj < n);
    const double* pb = M + (size_t)(ob ? gj : 0) * ld + k0 + lk;
#pragma unroll
    for (int q = 0; q < 4; ++q) {
      As[lk + q][li] = oa ? pa[q] : 0.0;
      Bs[lk + q][li] = ob ? pb[q] : 0.0;
    }
    __syncthreads();
#pragma unroll
    for (int kk = 0; kk < 16; ++kk) {
      double a[4], bb[4];
#pragma unroll
      for (int u = 0; u < 4; ++u) a[u] = As[kk][ty * 4 + u];
#pragma unroll
      for (int v = 0; v < 4; ++v) bb[v] = Bs[kk][tx * 4 + v];
#pragma unroll
      for (int u = 0; u < 4; ++u)
#pragma unroll
        for (int v = 0; v < 4; ++v) acc[u][v] += a[u] * bb[v];
    }
    __syncthreads();
  }
#pragma unroll
  for (int u = 0; u < 4; ++u) {
    int gi = bi + ty * 4 + u;
    if (gi >= n) continue;
#pragma unroll
    for (int v = 0; v < 4; ++v) {
      int gj = bj + tx * 4 + v;
      if (gj >= n) continue;
      double val = acc[u][v];
      C[(size_t)gi * ldc + gj] = val;
      if (by > bx) C[(size_t)gj * ldc + gi] = val;
    }
  }
}

// Multi-WG Householder tridiagonalization, panel-deferred rank-2NB updates (latrd-style).
// TDG WGs x 256 threads, ONE fence-free grid barrier per column. A rows WG-private; A is
// STALE (read-only) within a panel; V/W panels live in LDS (panel base b0=k0+1 indexing).
// xsh is GLOBAL-ROW indexed (xsh[r] = current column value at row r, support [k+1,n)) so
// no re-basing is needed at panel boundaries. Cross-WG per-column traffic: pvec + vtpp
// via sc0sc1; stale rows of the next panel dual-stored at panel end. Heavyweight gbar2
// only at the co-op -> single-WG-tail handoff.
__global__ __launch_bounds__(256) void k_tridiag_mw(double* __restrict__ A, int n, double* __restrict__ d,
                                                    double* __restrict__ e, double* __restrict__ tau,
                                                    double* __restrict__ Vrow, double* __restrict__ pvec,
                                                    double* __restrict__ vtpp, unsigned* __restrict__ flags) {
  __shared__ double Vp[NB][524];
  __shared__ double Wp[NB][524];
  __shared__ double xsh[524];
  __shared__ double xt[MTAIL + 8];
  __shared__ double redb[4];
  __shared__ double redb2[4];
  __shared__ double cvw[2 * NB];
  __shared__ double bc[1];
  const int tid = threadIdx.x, lane = tid & 63, wid = tid >> 6;
  const int g = blockIdx.x;
  unsigned gen = 0;
  const int ktail = n - 1 - MTAIL;  // first tail column (trailing size == MTAIL there)
  double dval = A[0];
  for (int r = 1 + tid; r < n; r += 256) xsh[r] = A[r];  // x for col 0 (= row 0), global-row base
  __syncthreads();

  for (int k0 = 0; k0 < ktail; k0 += NB) {
    const int pw = min(NB, ktail - k0);
    const int b0 = k0 + 1;
    const int m0 = n - b0;
    // zero panels (fixed-NB loops below rely on zero-padded unused rows)
    for (int l = 0; l < NB; ++l)
      for (int c = tid; c < m0; c += 256) {
        Vp[l][c] = 0.0;
        Wp[l][c] = 0.0;
      }
    __syncthreads();  // S0

    for (int j = 0; j < pw; ++j) {
      const int k = k0 + j;
      const int m = m0 - j;  // = n-1-k
      const int par = k & 1;
      double* __restrict__ pv = pvec + par * 520;
      double* __restrict__ vt = vtpp + par * 32;
      double* __restrict__ vsh = Vp[j];
      double* __restrict__ wsh = Wp[j];
      // ---- norm of x over rows [k+1, n) ----
      double part = 0.0;
      for (int r = k + 1 + tid; r < n; r += 256) part += xsh[r] * xsh[r];
      part = wred(part);
      if (lane == 0) redb[wid] = part;
      __syncthreads();  // S1
      double s2 = redb[0] + redb[1] + redb[2] + redb[3];
      double x0 = xsh[k + 1];
      double tk, v0, alpha;
      if (s2 < 1e-260) {
        tk = 0.0;
        v0 = 0.0;
        alpha = x0;
      } else {
        double sig = sqrt(s2);
        alpha = (x0 >= 0.0) ? -sig : sig;
        v0 = x0 - alpha;
        double vn2 = s2 - x0 * x0 + v0 * v0;
        tk = 2.0 / vn2;
      }
      for (int c = j + tid; c < m0; c += 256) vsh[c] = (c == j) ? v0 : xsh[b0 + c];
      __syncthreads();  // S2: vsh ready, redb consumed
      if (g == 0 && tid == 0) {
        d[k] = dval;
        e[k] = alpha;
        tau[k] = tk;
      }
      {  // distributed Vrow publish
        double* __restrict__ Vr = Vrow + (size_t)k * n;
        for (int i = g * 256 + tid; i < m; i += TDG * 256) Vr[i] = vsh[j + i];
      }
      // correction dots (W^T v, V^T v for l<j); unused slots zeroed
      if (tid >= 2 * j && tid < 2 * NB) cvw[tid] = 0.0;
      for (int t = wid; t < 2 * j; t += 4) {
        const int l = t >> 1;
        const double* __restrict__ src = (t & 1) ? Vp[l] : Wp[l];
        double acc = 0.0;
        for (int c = j + lane; c < m0; c += 64) acc += src[c] * vsh[c];
        acc = wred(acc);
        if (lane == 0) cvw[t] = acc;
      }
      __syncthreads();  // S3: cvw ready
      // ---- matvec p = tk*(A_stale·v − V(W^T v) − W(V^T v)) over own rows ----
      const int rem = (k + 1) & (TDG - 1);
      const int r0 = (k + 1) + ((g - rem + TDG) & (TDG - 1));
      double vtp = 0.0;
      for (int r = r0 + wid * TDG; r < n; r += 4 * TDG) {
        const int cr = r - b0;
        const int i = r - (k + 1);
        const double* __restrict__ row = A + (size_t)r * n + b0;
        double acc = 0.0;
        for (int c = j + lane; c < m0; c += 64) acc += row[c] * vsh[c];
        acc = wred(acc);
        if (lane == 0) {
          double corr = 0.0;
#pragma unroll
          for (int l = 0; l < NB; ++l) corr += Vp[l][cr] * cvw[2 * l] + Wp[l][cr] * cvw[2 * l + 1];
          double pi = tk * (acc - corr);
          stg(&pv[i], pi);
          vtp += vsh[cr] * pi;
        }
      }
      if (lane == 0) redb2[wid] = vtp;
      __syncthreads();  // S4
      if (tid == 0) stg(&vt[g], redb2[0] + redb2[1] + redb2[2] + redb2[3]);
      gbarf(flags, gen);  // B: pv, vt visible everywhere
      // ---- post-barrier: K0, w ----
      if (wid == 0) {
        double vv = (lane < TDG) ? ldg_(&vt[lane]) : 0.0;
        vv = wred(vv);
        if (lane == 0) bc[0] = vv;
      }
      __syncthreads();  // S5
      const double K0 = 0.5 * tk * bc[0];
      for (int c = j + tid; c < m0; c += 256) wsh[c] = ldg_(&pv[c - j]) - K0 * vsh[c];
      __syncthreads();  // S6: wsh ready
      // ---- next column x from STALE row k+1 (coherent reads) + panel corrections ----
      {
        const double* __restrict__ srow = A + (size_t)(k + 1) * n + b0;
        for (int c = j + 1 + tid; c < m0; c += 256) {
          double acc = ldg_(&srow[c]);
#pragma unroll
          for (int l = 0; l < NB; ++l) acc -= Vp[l][j] * Wp[l][c] + Wp[l][j] * Vp[l][c];
          xsh[b0 + c] = acc;
        }
        if (tid == 0) {
          double acc = ldg_(&srow[j]);  // stale A[k+1][k+1]
#pragma unroll
          for (int l = 0; l < NB; ++l) acc -= 2.0 * Vp[l][j] * Wp[l][j];
          dval = acc;
        }
      }
      __syncthreads();  // S7: xsh stable for next column
    }

    // ---- panel-end: rank-2*pw update of own rows r in (k0+pw, n), cols common [pw, m0) ----
    {
      const int kend = k0 + pw;
      const int rem = (kend + 1) & (TDG - 1);
      const int r0 = (kend + 1) + ((g - rem + TDG) & (TDG - 1));
      for (int r = r0 + wid * TDG; r < n; r += 4 * TDG) {
        const int cr = r - b0;
        double vlr[NB], wlr[NB];
#pragma unroll
        for (int l = 0; l < NB; ++l) {
          vlr[l] = Vp[l][cr];
          wlr[l] = Wp[l][cr];
        }
        double* __restrict__ row = A + (size_t)r * n + b0;
        const bool wt = (r <= kend + NB);  // stale rows of next panel: dual store (own L2 + L3)
        for (int c = pw + lane; c < m0; c += 64) {
          double a = row[c];
#pragma unroll
          for (int l = 0; l < NB; ++l) a -= vlr[l] * Wp[l][c] + wlr[l] * Vp[l][c];
          row[c] = a;
          if (wt) stg(&row[c], a);
        }
      }
    }
    __syncthreads();  // S8: panel reads done before next panel zeroes Vp/Wp
  }

  gbar2(flags, gen);  // heavyweight: bulk A updates visible before WG0 tail
  if (g != 0) return;
  // ---- single-WG tail: k = ktail .. n-3 ----
  for (int i = tid; i < n - 1 - ktail; i += 256) xt[i] = xsh[ktail + 1 + i];
  double* __restrict__ vsh = Vp[0];
  double* __restrict__ wsh = Wp[0];
  __syncthreads();
  for (int k = ktail; k <= n - 3; ++k) {
    const int m = n - 1 - k;
    double part = 0.0;
    for (int i = tid; i < m; i += 256) {
      double xi = xt[i];
      vsh[i] = xi;
      part += xi * xi;
    }
    part = wred(part);
    if (lane == 0) redb[wid] = part;
    __syncthreads();
    double s2 = redb[0] + redb[1] + redb[2] + redb[3];
    double x0 = vsh[0];
    double tk, v0, alpha;
    if (s2 < 1e-260) {
      tk = 0.0;
      v0 = 0.0;
      alpha = x0;
    } else {
      double sig = sqrt(s2);
      alpha = (x0 >= 0.0) ? -sig : sig;
      v0 = x0 - alpha;
      double vn2 = s2 - x0 * x0 + v0 * v0;
      tk = 2.0 / vn2;
    }
    __syncthreads();
    if (tid == 0) {
      vsh[0] = v0;
      d[k] = (k == ktail) ? dval : A[(size_t)k * n + k];
      e[k] = alpha;
      tau[k] = tk;
    }
    __syncthreads();
    double* __restrict__ Vr = Vrow + (size_t)k * n;
    for (int i = tid; i < m; i += 256) Vr[i] = vsh[i];
    // matvec, wave-per-row
    double vtp = 0.0;
    for (int i = wid; i < m; i += 4) {
      const double* __restrict__ row = A + (size_t)(k + 1 + i) * n + (k + 1);
      double acc = 0.0;
      for (int j = lane; j < m; j += 64) acc += row[j] * vsh[j];
      acc = wred(acc);
      if (lane == 0) {
        double pi = tk * acc;
        wsh[i] = pi;
        vtp += vsh[i] * pi;
      }
    }
    if (lane == 0) redb2[wid] = vtp;
    __syncthreads();
    const double K0 = 0.5 * tk * (redb2[0] + redb2[1] + redb2[2] + redb2[3]);
    for (int i = wid; i < m; i += 4) {
      const double vi = vsh[i];
      const double ci = wsh[i] - 2.0 * K0 * vsh[i];
      double* __restrict__ row = A + (size_t)(k + 1 + i) * n + (k + 1);
      for (int j = lane; j < m; j += 64) {
        double nv = row[j] - (vi * wsh[j] + ci * vsh[j]);
        row[j] = nv;
        if (j == 0 && i >= 1) xt[i - 1] = nv;
      }
    }
    __syncthreads();
  }
  if (tid == 0) {
    d[n - 2] = A[(size_t)(n - 2) * n + (n - 2)];
    e[n - 2] = A[(size_t)(n - 1) * n + (n - 2)];
    d[n - 1] = A[(size_t)(n - 1) * n + (n - 1)];
  }
}

// Bisection (34 rounds), eigenvalues split across WGs of 64.
__global__ __launch_bounds__(64) void k_bisect_mw(const double* __restrict__ d, const double* __restrict__ e, int n,
                                                  double* __restrict__ lam) {
  __shared__ double ds[520];
  __shared__ double e2s[520];
  __shared__ double bc[4];
  const int tid = threadIdx.x;
  for (int i = tid; i < n; i += 64) {
    ds[i] = d[i];
    e2s[i] = (i >= 1) ? e[i - 1] * e[i - 1] : 0.0;
  }
  __syncthreads();
  if (tid == 0) {
    double glo = 1e300, ghi = -1e300, me2 = 0.0;
    for (int i = 0; i < n; ++i) {
      double ea = (i >= 1) ? sqrt(e2s[i]) : 0.0;
      double eb = (i < n - 1) ? sqrt(e2s[i + 1]) : 0.0;
      glo = fmin(glo, ds[i] - ea - eb);
      ghi = fmax(ghi, ds[i] + ea + eb);
      me2 = fmax(me2, e2s[i]);
    }
    double span = ghi - glo;
    bc[0] = glo - 1e-3 * span - 1e-30;
    bc[1] = ghi + 1e-3 * span + 1e-30;
    bc[2] = fmax(me2 * 2.220446049250313e-16, 1e-280);
  }
  __syncthreads();
  const int idx = blockIdx.x * 64 + tid;
  if (idx < n) {
    double lo = bc[0], hi = bc[1];
    const double pivmin = bc[2];
    for (int r = 0; r < 34; ++r) {
      double x = 0.5 * (lo + hi);
      int cnt = 0;
      double q = ds[0] - x;
      if (q < 0.0) cnt++;
      for (int i = 1; i < n; ++i) {
        double t = q;
        if (fabs(t) < pivmin) t = (t < 0.0) ? -pivmin : pivmin;
        q = (ds[i] - x) - e2s[i] / t;
        if (q < 0.0) cnt++;
      }
      if (cnt <= idx) lo = x;
      else hi = x;
    }
    lam[idx] = 0.5 * (lo + hi);
  }
}

// Spectral readout.
__global__ __launch_bounds__(64) void k_specsum(const double* __restrict__ lam, int n, int keep_start, int step,
                                                float* __restrict__ out, double* __restrict__ scal) {
  if (threadIdx.x == 0) {
    int cnt = 0;
    double st = 0.0, sa = 0.0;
    for (int i = 0; i < n; ++i) {
      double l = lam[i];
      double s = (l > 0.0) ? sqrt(l) : 0.0;
      if (s > 1e-5) cnt++;
      sa += s;
      if (i >= keep_start) st += s;
    }
    bool trunc = (cnt > 321);
    double ssum = trunc ? st : sa;
    const double NORMF = 1448.1546878700494;  // sqrt(4096*512)
    double l1 = ssum / NORMF;
    out[step] = (float)l1;
    scal[S_SCALE] = (l1 > 15.045) ? (15.045 / l1) : 1.0;
  }
}

// Fused: tridiag inverse iteration (thread 0) -> HH chain (1 wave) -> vhh + g. Steps 2..30 (n<=384).
__global__ __launch_bounds__(512) void k_eigvec(const double* __restrict__ Vrow, int n, const double* __restrict__ d,
                                                const double* __restrict__ e, const double* __restrict__ tau,
                                                const double* __restrict__ lam, const double* __restrict__ Mm,
                                                const double* __restrict__ tvec, double* __restrict__ scal,
                                                double* __restrict__ vhh, double* __restrict__ g) {
  __shared__ double zs[384];
  __shared__ double cps[384];
  __shared__ double dsh[384];
  __shared__ double esh[384];
  __shared__ double tsh[384];
  __shared__ double tvsh[384];
  __shared__ double bc[2];
  const int tid = threadIdx.x;
  for (int i = tid; i < n; i += 512) {
    dsh[i] = d[i];
    esh[i] = e[i];
    tsh[i] = tau[i];
    tvsh[i] = tvec[i];
  }
  __syncthreads();
  if (tid == 0) {
    double lmax = fabs(lam[n - 1]);
    double sh = lam[0] - (1e-12 * lmax + 1e-280);
    double me2 = 0.0;
    for (int i = 1; i < n; ++i) {
      double t = esh[i - 1];
      me2 = fmax(me2, t * t);
    }
    double pivmin = fmax(me2 * 2.220446049250313e-16, 1e-280);
    unsigned s = 0xB5297A4Du;
    for (int i = 0; i < n; ++i) {
      s = s * 1664525u + 1013904223u;
      zs[i] = 0.75 + (double)(s >> 8) * (0.5 / 16777216.0);
    }
    for (int it = 0; it < 3; ++it) {
      double den = dsh[0] - sh;
      if (fabs(den) < pivmin) den = (den < 0) ? -pivmin : pivmin;
      cps[0] = esh[0] / den;
      zs[0] = zs[0] / den;
      for (int i = 1; i < n; ++i) {
        den = (dsh[i] - sh) - esh[i - 1] * cps[i - 1];
        if (fabs(den) < pivmin) den = (den < 0) ? -pivmin : pivmin;
        cps[i] = (i < n - 1) ? esh[i] / den : 0.0;
        zs[i] = (zs[i] - esh[i - 1] * zs[i - 1]) / den;
      }
      for (int i = n - 2; i >= 0; --i) zs[i] -= cps[i] * zs[i + 1];
      double nn = 0;
      for (int i = 0; i < n; ++i) nn += zs[i] * zs[i];
      double inv = 1.0 / sqrt(fmax(nn, 1e-300));
      for (int i = 0; i < n; ++i) zs[i] *= inv;
    }
  }
  __syncthreads();
  if (tid < 64) {
    double z[6];
#pragma unroll
    for (int r = 0; r < 6; ++r) {
      int j = tid + 64 * r;
      z[r] = (j < n) ? zs[j] : 0.0;
    }
    for (int k = n - 3; k >= 0; --k) {
      const double tk = tsh[k];
      const double* __restrict__ vr = Vrow + (size_t)k * n;
      double vv[6];
#pragma unroll
      for (int r = 0; r < 6; ++r) {
        int j = tid + 64 * r;
        vv[r] = (j >= k + 1 && j < n) ? vr[j - k - 1] : 0.0;
      }
      double p = 0.0;
#pragma unroll
      for (int r = 0; r < 6; ++r) p += vv[r] * z[r];
      p = wred(p);
      p = __shfl(p, 0, 64);
      double tp = tk * p;
#pragma unroll
      for (int r = 0; r < 6; ++r) z[r] -= tp * vv[r];
    }
    double nn = 0.0;
#pragma unroll
    for (int r = 0; r < 6; ++r) nn += z[r] * z[r];
    nn = wred(nn);
    nn = __shfl(nn, 0, 64);
    double inv = 1.0 / sqrt(fmax(nn, 1e-300));
#pragma unroll
    for (int r = 0; r < 6; ++r) {
      int j = tid + 64 * r;
      if (j < n) zs[j] = z[r] * inv;
    }
  }
  __syncthreads();
  if (tid == 0) {
    double wl = zs[n - 1];
    double sg = (wl >= 0.0) ? 1.0 : -1.0;
    double coef = 1.0 / (1.0 + fabs(wl));
    zs[n - 1] = wl + sg;
    scal[S_VTV] = 2.0 + 2.0 * fabs(wl);
    bc[0] = coef;
    double sc = 0.0;
    for (int i = 0; i < n; ++i) sc += zs[i] * tvsh[i];
    scal[S_SC] = sc * coef;
  }
  __syncthreads();
  const double coef = bc[0];
  {
    double acc = 0.0;
    for (int i = 0; i < n; ++i) acc += zs[i] * Mm[(size_t)i * DIM + tid];
    g[tid] = coef * acc;
  }
  for (int i = tid; i < n; i += 512) vhh[i] = zs[i];
}

// step-1: inverse iteration for the 321 kept tridiag eigenvectors + neighbor reorth
__global__ __launch_bounds__(512) void k_ii_multi(const double* __restrict__ d, const double* __restrict__ e,
                                                  const double* __restrict__ lam, int n, int keep_start,
                                                  double* __restrict__ Uk, double* __restrict__ cp) {
  const int tid = threadIdx.x, lane = tid & 63, wid = tid >> 6;
  __shared__ double redb[8];
  __shared__ double bc[1];
  if (tid < KEEP) {
    int j = tid;
    double lj = lam[keep_start + j];
    double me2 = 0.0;
    for (int i = 1; i < n; ++i) {
      double t = e[i - 1];
      me2 = fmax(me2, t * t);
    }
    double pivmin = fmax(me2 * 2.220446049250313e-16, 1e-280);
    unsigned s = 0x9E3779B9u * (unsigned)(j + 13);
    for (int i = 0; i < n; ++i) {
      s = s * 1664525u + 1013904223u;
      Uk[(size_t)i * KEEP + j] = 0.5 + (double)(s >> 8) * (1.0 / 16777216.0);
    }
    for (int it = 0; it < 3; ++it) {
      double den = d[0] - lj;
      if (fabs(den) < pivmin) den = (den < 0.0) ? -pivmin : pivmin;
      double cprev = e[0] / den;
      cp[0 * KEEP + j] = cprev;
      double zprev = Uk[0 * KEEP + j] / den;
      Uk[0 * KEEP + j] = zprev;
      for (int i = 1; i < n; ++i) {
        den = (d[i] - lj) - e[i - 1] * cprev;
        if (fabs(den) < pivmin) den = (den < 0.0) ? -pivmin : pivmin;
        double ci = (i < n - 1) ? e[i] / den : 0.0;
        cp[(size_t)i * KEEP + j] = ci;
        double zi = (Uk[(size_t)i * KEEP + j] - e[i - 1] * zprev) / den;
        Uk[(size_t)i * KEEP + j] = zi;
        zprev = zi;
        cprev = ci;
      }
      double zn = Uk[(size_t)(n - 1) * KEEP + j];
      for (int i = n - 2; i >= 0; --i) {
        zn = Uk[(size_t)i * KEEP + j] - cp[(size_t)i * KEEP + j] * zn;
        Uk[(size_t)i * KEEP + j] = zn;
      }
      double nn = 0;
      for (int i = 0; i < n; ++i) {
        double z = Uk[(size_t)i * KEEP + j];
        nn += z * z;
      }
      double inv = 1.0 / sqrt(fmax(nn, 1e-300));
      for (int i = 0; i < n; ++i) Uk[(size_t)i * KEEP + j] *= inv;
    }
  }
  __syncthreads();
  for (int jj = 1; jj < KEEP; ++jj) {
    double l1v = lam[keep_start + jj], l0v = lam[keep_start + jj - 1];
    bool close = (l1v - l0v) < 1e-7 * (fabs(l1v) + 1e-280);
    if (!close) continue;
    double p = 0;
    for (int i = tid; i < n; i += 512) p += Uk[(size_t)i * KEEP + jj] * Uk[(size_t)i * KEEP + jj - 1];
    p = wred(p);
    if (lane == 0) redb[wid] = p;
    __syncthreads();
    if (tid == 0) {
      double s2 = 0;
      for (int q = 0; q < 8; ++q) s2 += redb[q];
      bc[0] = s2;
    }
    __syncthreads();
    double dot = bc[0];
    for (int i = tid; i < n; i += 512) Uk[(size_t)i * KEEP + jj] -= dot * Uk[(size_t)i * KEEP + jj - 1];
    __syncthreads();
    p = 0;
    for (int i = tid; i < n; i += 512) {
      double z = Uk[(size_t)i * KEEP + jj];
      p += z * z;
    }
    p = wred(p);
    if (lane == 0) redb[wid] = p;
    __syncthreads();
    if (tid == 0) {
      double s2 = 0;
      for (int q = 0; q < 8; ++q) s2 += redb[q];
      bc[0] = 1.0 / sqrt(fmax(s2, 1e-300));
    }
    __syncthreads();
    double inv = bc[0];
    for (int i = tid; i < n; i += 512) Uk[(size_t)i * KEEP + jj] *= inv;
    __syncthreads();
  }
}

// apply stored Householder chain to each kept eigenvector (one wave per column)
__global__ __launch_bounds__(64) void k_hhapply_multi(const double* __restrict__ Vrow, const double* __restrict__ tau,
                                                      int n, double* __restrict__ Uk) {
  const int j = blockIdx.x;
  const int lane = threadIdx.x;
  for (int k = n - 3; k >= 0; --k) {
    double tk = tau[k];
    if (tk == 0.0) continue;
    int m = n - 1 - k;
    const double* __restrict__ vr = Vrow + (size_t)k * n;
    double p = 0.0;
    for (int i = lane; i < m; i += 64) p += vr[i] * Uk[(size_t)(k + 1 + i) * KEEP + j];
    p = wred(p);
    p = __shfl(p, 0, 64);
    double tp = tk * p;
    for (int i = lane; i < m; i += 64) Uk[(size_t)(k + 1 + i) * KEEP + j] -= tp * vr[i];
  }
  double nn = 0.0;
  for (int i = lane; i < n; i += 64) {
    double z = Uk[(size_t)i * KEEP + j];
    nn += z * z;
  }
  nn = wred(nn);
  nn = __shfl(nn, 0, 64);
  double inv = 1.0 / sqrt(fmax(nn, 1e-300));
  for (int i = lane; i < n; i += 64) Uk[(size_t)i * KEEP + j] *= inv;
}

// C[MxN] = s * A^T·B
__global__ __launch_bounds__(256) void k_gemm_tn(const double* __restrict__ A, const double* __restrict__ B,
                                                 double* __restrict__ C, int M, int N, int Kd, int lda, int ldb, int ldc,
                                                 const double* __restrict__ scal) {
  __shared__ double As[16][65];
  __shared__ double Bs[16][65];
  const int tid = threadIdx.x;
  const int tx = tid & 15, ty = tid >> 4;
  const int bi = blockIdx.y * 64, bj = blockIdx.x * 64;
  const int li = tid & 63, lq = tid >> 6;
  double acc[4][4] = {};
  for (int k0 = 0; k0 < Kd; k0 += 16) {
#pragma unroll
    for (int q = 0; q < 4; ++q) {
      int kk = lq + q * 4;
      int gk = k0 + kk;
      int gi = bi + li;
      int gj = bj + li;
      As[kk][li] = (gi < M && gk < Kd) ? A[(size_t)gk * lda + gi] : 0.0;
      Bs[kk][li] = (gj < N && gk < Kd) ? B[(size_t)gk * ldb + gj] : 0.0;
    }
    __syncthreads();
#pragma unroll
    for (int kk = 0; kk < 16; ++kk) {
      double a[4], bb[4];
#pragma unroll
      for (int u = 0; u < 4; ++u) a[u] = As[kk][ty * 4 + u];
#pragma unroll
      for (int v = 0; v < 4; ++v) bb[v] = Bs[kk][tx * 4 + v];
#pragma unroll
      for (int u = 0; u < 4; ++u)
#pragma unroll
        for (int v = 0; v < 4; ++v) acc[u][v] += a[u] * bb[v];
    }
    __syncthreads();
  }
  double s = scal[S_SCALE];
#pragma unroll
  for (int u = 0; u < 4; ++u) {
    int gi = bi + ty * 4 + u;
    if (gi >= M) continue;
#pragma unroll
    for (int v = 0; v < 4; ++v) {
      int gj = bj + tx * 4 + v;
      if (gj >= N) continue;
      C[(size_t)gi * ldc + gj] = s * acc[u][v];
    }
  }
}

// c_state = Uk^T tvec
__global__ __launch_bounds__(512) void k_gemv_tn(const double* __restrict__ Uk, const double* __restrict__ tvec,
                                                 double* __restrict__ cstv, int n) {
  int i = threadIdx.x;
  if (i < KEEP) {
    double acc = 0.0;
    for (int k = 0; k < n; ++k) acc += Uk[(size_t)k * KEEP + i] * tvec[k];
    cstv[i] = acc;
  }
}

// C_state = scale*(M - v g^T) rows 0..320 ;  c_state = (tvec - v*sc)[0..320]
__global__ __launch_bounds__(256) void k_hh_update(const double* __restrict__ Mm, const double* __restrict__ vhh,
                                                   const double* __restrict__ g, const double* __restrict__ scal,
                                                   const double* __restrict__ tvec, double* __restrict__ Cst,
                                                   double* __restrict__ cstv) {
  int idx = blockIdx.x * 256 + threadIdx.x;
  double scale = scal[S_SCALE];
  if (idx < KEEP * DIM) {
    int i = idx >> 9, j = idx & 511;
    Cst[(size_t)i * DIM + j] = scale * (Mm[(size_t)i * DIM + j] - vhh[i] * g[j]);
  }
  if (blockIdx.x == 0 && threadIdx.x < KEEP) {
    cstv[threadIdx.x] = tvec[threadIdx.x] - vhh[threadIdx.x] * scal[S_SC];
  }
}

// ---------------- host ----------------

extern "C" void kernel_launch(void* const* d_in, const int* in_sizes, int n_in, void* d_out, int out_size, void* d_ws,
                              size_t ws_size, hipStream_t stream) {
  (void)in_sizes;
  (void)n_in;
  (void)out_size;
  (void)ws_size;
  const float* x = (const float*)d_in[0];
  const float* W = (const float*)d_in[1];
  const float* b = (const float*)d_in[2];
  float* out = (float*)d_out;

  char* ws = (char*)d_ws;
  size_t off = 0;
  auto alloc = [&](size_t nelem) {
    size_t p = off;
    off += (nelem * 8 + 255) & ~(size_t)255;
    return (double*)(ws + p);
  };
  double* Wd = alloc(512 * 512);
  double* bd = alloc(512);
  double* mvec = alloc(512);
  double* Cst = alloc(512 * 512);
  double* cstv = alloc(520);
  double* tvec = alloc(520);
  double* Mm = alloc(513 * 512);
  double* AwGx = alloc(513 * 513);
  double* Gx = AwGx;
  double* Aw = AwGx;
  double* zcp = AwGx;
  double* Vrow = alloc(513 * 513);
  double* dT = alloc(520);
  double* eT = alloc(520);
  double* tauT = alloc(520);
  double* lam = alloc(520);
  double* vhh = alloc(520);
  double* gv = alloc(520);
  double* scal = alloc(32);
  double* Uk = alloc(513 * 321);
  // multi-WG shared buffers (pvec/vtpp double-buffered by column parity)
  double* pvec = alloc(1040);
  double* vtpp = alloc(64);
  unsigned* tflags = (unsigned*)alloc(512);  // 1024 uints, tridiag barrier
  unsigned* cflags = (unsigned*)alloc(512);  // 1024 uints, chol barrier
  // total ~12.0 MB

  // ---- setup ----
  k_cast<<<dim3((512 * 512 + 255) / 256), dim3(256), 0, stream>>>(W, b, Wd, bd, cflags);
  k_colsum<<<dim3(1), dim3(512), 0, stream>>>(x, mvec);
  k_xtx<<<dim3(8, 8), dim3(256), 0, stream>>>(x, Gx);
  k_chol_mw<<<dim3(TDG), dim3(256), 0, stream>>>(Gx, Cst, cflags);
  k_solvec0<<<dim3(1), dim3(64), 0, stream>>>(Cst, mvec, cstv);

  // ---- step 1 (r=512, n=513) ----
  {
    const int r = 512, n = 513;
    k_prep<<<dim3(1), dim3(512), 0, stream>>>(cstv, bd, r, tvec, Mm, scal, tflags);
    k_gemm_nt<<<dim3(8, 8), dim3(256), 0, stream>>>(Cst, Wd, Mm, r, 512, 512, 512, 512, 512, cstv, bd);
    k_syrk<<<dim3(45), dim3(256), 0, stream>>>(Mm, Aw, n, 512, 512, n);
    k_tridiag_mw<<<dim3(TDG), dim3(256), 0, stream>>>(Aw, n, dT, eT, tauT, Vrow, pvec, vtpp, tflags);
    k_bisect_mw<<<dim3((n + 63) / 64), dim3(64), 0, stream>>>(dT, eT, n, lam);
    k_specsum<<<dim3(1), dim3(64), 0, stream>>>(lam, n, n - KEEP, 0, out, scal);
    k_ii_multi<<<dim3(1), dim3(512), 0, stream>>>(dT, eT, lam, n, n - KEEP, Uk, zcp);
    k_hhapply_multi<<<dim3(KEEP), dim3(64), 0, stream>>>(Vrow, tauT, n, Uk);
    k_gemm_tn<<<dim3(8, 6), dim3(256), 0, stream>>>(Uk, Mm, Cst, KEEP, 512, n, KEEP, 512, 512, scal);
    k_gemv_tn<<<dim3(1), dim3(512), 0, stream>>>(Uk, tvec, cstv, n);
  }

  // ---- steps 2..30 (r=321, n=322) ----
  for (int t = 1; t < NSTEPS; ++t) {
    const int r = KEEP, n = KEEP + 1;
    k_prep<<<dim3(1), dim3(512), 0, stream>>>(cstv, bd, r, tvec, Mm, scal, tflags);
    k_gemm_nt<<<dim3(8, 6), dim3(256), 0, stream>>>(Cst, Wd, Mm, r, 512, 512, 512, 512, 512, cstv, bd);
    k_syrk<<<dim3(21), dim3(256), 0, stream>>>(Mm, Aw, n, 512, 512, n);
    k_tridiag_mw<<<dim3(TDG), dim3(256), 0, stream>>>(Aw, n, dT, eT, tauT, Vrow, pvec, vtpp, tflags);
    k_bisect_mw<<<dim3((n + 63) / 64), dim3(64), 0, stream>>>(dT, eT, n, lam);
    k_specsum<<<dim3(1), dim3(64), 0, stream>>>(lam, n, 1, t, out, scal);
    k_eigvec<<<dim3(1), dim3(512), 0, stream>>>(Vrow, n, dT, eT, tauT, lam, Mm, tvec, scal, vhh, gv);
    k_hh_update<<<dim3((KEEP * DIM + 255) / 256), dim3(256), 0, stream>>>(Mm, vhh, gv, scal, tvec, Cst, cstv);
  }
}

// Round 8
// 144666.418 us; speedup vs baseline: 1.2759x; 1.2759x over previous
//
#include <hip/hip_runtime.h>
#include <math.h>

#define DIM 512
#define BATCH 4096
#define NSTEPS 30
#define KEEP 321

#define S_BETA 0
#define S_SCALE 1
#define S_VTV 4
#define S_SC 5

#define TDG 32     // workgroups cooperating in k_tridiag_mw / k_chol_mw
#define MTAIL 128  // tridiag: below this trailing size, WG0 finishes alone (no grid barriers)

__device__ __forceinline__ double wred(double v) {
#pragma unroll
  for (int o = 32; o > 0; o >>= 1) v += __shfl_down(v, (unsigned)o, 64);
  return v;
}

// Agent-scope (device) relaxed atomics: sc0|sc1 accesses that write-through / read-through
// the die-level coherence point. No L2 writeback/invalidate involved.
__device__ __forceinline__ void stg(double* p, double v) {
  __hip_atomic_store(p, v, __ATOMIC_RELAXED, __HIP_MEMORY_SCOPE_AGENT);
}
__device__ __forceinline__ double ldg_(const double* p) {
  return __hip_atomic_load(p, __ATOMIC_RELAXED, __HIP_MEMORY_SCOPE_AGENT);
}

// Heavyweight grid barrier (full agent fences) — ONLY where bulk L2-cached data must
// become visible across WGs (co-op -> tail handoff in tridiag).
__device__ __forceinline__ void gbar2(unsigned* __restrict__ flags, unsigned& gen) {
  gen++;
  const unsigned target = gen;
  __syncthreads();
  if (threadIdx.x == 0) {
    __threadfence();
    __hip_atomic_store(flags + (size_t)blockIdx.x * 32, target, __ATOMIC_RELAXED, __HIP_MEMORY_SCOPE_AGENT);
  }
  if (threadIdx.x < 64) {
    bool ok = ((int)threadIdx.x >= TDG);
    while (!__all(ok)) {
      if (!ok) {
        unsigned v = __hip_atomic_load(flags + (size_t)threadIdx.x * 32, __ATOMIC_RELAXED, __HIP_MEMORY_SCOPE_AGENT);
        ok = (v >= target);
      }
    }
    __threadfence();
  }
  __syncthreads();
}

// Fence-free grid barrier: all cross-WG data goes through stg/ldg_ (sc0sc1).
__device__ __forceinline__ void gbarf(unsigned* __restrict__ flags, unsigned& gen) {
  gen++;
  const unsigned target = gen;
  __syncthreads();
  if (threadIdx.x == 0) {
    __hip_atomic_store(flags + (size_t)blockIdx.x * 32, target, __ATOMIC_RELAXED, __HIP_MEMORY_SCOPE_AGENT);
  }
  if (threadIdx.x < 64) {
    bool ok = ((int)threadIdx.x >= TDG);
    while (!__all(ok)) {
      if (!ok) {
        unsigned v = __hip_atomic_load(flags + (size_t)threadIdx.x * 32, __ATOMIC_RELAXED, __HIP_MEMORY_SCOPE_AGENT);
        ok = (v >= target);
      }
    }
    asm volatile("" ::: "memory");
  }
  __syncthreads();
}

// ---------------- setup kernels ----------------

__global__ __launch_bounds__(256) void k_cast(const float* __restrict__ W, const float* __restrict__ b,
                                              double* __restrict__ Wd, double* __restrict__ bd,
                                              unsigned* __restrict__ cflags) {
  int idx = blockIdx.x * 256 + threadIdx.x;
  if (idx < DIM * DIM) Wd[idx] = (double)W[idx];
  if (idx < DIM) bd[idx] = (double)b[idx];
  if (blockIdx.x == 0) {
    for (int i = threadIdx.x; i < 1024; i += 256) cflags[i] = 0;
  }
}

__global__ __launch_bounds__(512) void k_colsum(const float* __restrict__ x, double* __restrict__ mvec) {
  int j = threadIdx.x;
  double s = 0.0;
  for (int r = 0; r < BATCH; ++r) s += (double)x[(size_t)r * DIM + j];
  mvec[j] = s;
}

// Gx = x^T x in fp64 (x fp32).
__global__ __launch_bounds__(256) void k_xtx(const float* __restrict__ x, double* __restrict__ Gx) {
  __shared__ double As[16][65];
  __shared__ double Bs[16][65];
  const int tid = threadIdx.x;
  const int tx = tid & 15, ty = tid >> 4;
  const int bi = blockIdx.y * 64, bj = blockIdx.x * 64;
  const int lr = tid >> 4, lc4 = (tid & 15) * 4;
  double acc[4][4] = {};
  for (int r0 = 0; r0 < BATCH; r0 += 16) {
#pragma unroll
    for (int q = 0; q < 4; ++q) {
      As[lr][lc4 + q] = (double)x[(size_t)(r0 + lr) * DIM + bi + lc4 + q];
      Bs[lr][lc4 + q] = (double)x[(size_t)(r0 + lr) * DIM + bj + lc4 + q];
    }
    __syncthreads();
#pragma unroll
    for (int rr = 0; rr < 16; ++rr) {
      double a[4], bb[4];
#pragma unroll
      for (int u = 0; u < 4; ++u) a[u] = As[rr][ty * 4 + u];
#pragma unroll
      for (int v = 0; v < 4; ++v) bb[v] = Bs[rr][tx * 4 + v];
#pragma unroll
      for (int u = 0; u < 4; ++u)
#pragma unroll
        for (int v = 0; v < 4; ++v) acc[u][v] += a[u] * bb[v];
    }
    __syncthreads();
  }
#pragma unroll
  for (int u = 0; u < 4; ++u)
#pragma unroll
    for (int v = 0; v < 4; ++v) Gx[(size_t)(bi + ty * 4 + u) * DIM + bj + tx * 4 + v] = acc[u][v];
}

// Multi-WG Cholesky Gx = R^T R (R upper, lower zeroed), TDG WGs.
__global__ __launch_bounds__(256) void k_chol_mw(const double* __restrict__ G, double* __restrict__ R,
                                                 unsigned* __restrict__ flags) {
  __shared__ double Lr[16][512];
  __shared__ double rowk[512];
  const int tid = threadIdx.x, lane = tid & 63, wid = tid >> 6;
  const int g = blockIdx.x;
  unsigned gen = 0;
  for (int s = 0; s < 16; ++s) {
    const int i = s * 32 + g;
    for (int j = tid; j < DIM; j += 256) Lr[s][j] = G[(size_t)i * DIM + j];
  }
  __syncthreads();
  for (int k = 0; k < DIM; ++k) {
    if ((k & 31) == g) {
      const int s = k >> 5;
      double dkk = Lr[s][k];
      double sq = sqrt(fmax(dkk, 1e-280));
      double inv = 1.0 / sq;
      for (int j = tid; j < DIM; j += 256) {
        double v;
        if (j < k) v = 0.0;
        else if (j == k) v = sq;
        else v = Lr[s][j] * inv;
        stg(&R[(size_t)k * DIM + j], v);
      }
    }
    gbarf(flags, gen);
    for (int j = k + tid; j < DIM; j += 256) rowk[j] = ldg_(&R[(size_t)k * DIM + j]);
    __syncthreads();
    for (int s = wid; s < 16; s += 4) {
      const int i = s * 32 + g;
      if (i <= k) continue;
      const double rki = rowk[i];
      for (int j = i + lane; j < DIM; j += 64) Lr[s][j] -= rki * rowk[j];
    }
    __syncthreads();
  }
}

// forward-substitution R^T c0 = mvec — single wave, rhs in registers, no barriers
__global__ __launch_bounds__(64) void k_solvec0(const double* __restrict__ R, const double* __restrict__ mvec,
                                                double* __restrict__ c0) {
  const int lane = threadIdx.x;
  double rhs[8], cs[8];
#pragma unroll
  for (int r = 0; r < 8; ++r) rhs[r] = mvec[lane + 64 * r];
#pragma unroll
  for (int r = 0; r < 8; ++r) cs[r] = 0.0;
  for (int i = 0; i < DIM; ++i) {
    int owner = i & 63, ri = i >> 6;
    double ci = 0.0;
    if (lane == owner) {
      ci = rhs[ri] / R[(size_t)i * DIM + i];
      cs[ri] = ci;
    }
    ci = __shfl(ci, owner, 64);
    const double* row = R + (size_t)i * DIM;
#pragma unroll
    for (int r = 0; r < 8; ++r) {
      int j = lane + 64 * r;
      if (j > i) rhs[r] -= ci * row[j];
    }
  }
#pragma unroll
  for (int r = 0; r < 8; ++r) c0[lane + 64 * r] = cs[r];
}

// ---------------- per-step kernels ----------------

__global__ __launch_bounds__(512) void k_prep(const double* __restrict__ cstv, const double* __restrict__ bd, int r,
                                              double* __restrict__ tvec, double* __restrict__ Mm,
                                              double* __restrict__ scal, unsigned* __restrict__ tflags) {
  __shared__ double redb[8];
  __shared__ double bc[1];
  const int tid = threadIdx.x, lane = tid & 63, wid = tid >> 6;
  for (int i = tid; i < 1024; i += 512) tflags[i] = 0;  // reset tridiag barrier flags
  double p = 0.0;
  for (int i = tid; i < r; i += 512) {
    double c = cstv[i];
    p += c * c;
    tvec[i] = c;
  }
  p = wred(p);
  if (lane == 0) redb[wid] = p;
  __syncthreads();
  if (tid == 0) {
    double s = 0;
    for (int q = 0; q < 8; ++q) s += redb[q];
    double beta = sqrt(fmax(4096.0 - s, 1e-20));
    tvec[r] = beta;
    scal[S_BETA] = beta;
    bc[0] = beta;
  }
  __syncthreads();
  double beta = bc[0];
  for (int j = tid; j < DIM; j += 512) Mm[(size_t)r * DIM + j] = beta * bd[j];
}

// C[MxN] = A·B^T (+ ur·vr^T), row-major, fp64.
__global__ __launch_bounds__(256) void k_gemm_nt(const double* __restrict__ A, const double* __restrict__ B,
                                                 double* __restrict__ C, int M, int N, int Kd, int lda, int ldb, int ldc,
                                                 const double* __restrict__ ur, const double* __restrict__ vr) {
  __shared__ double As[16][65];
  __shared__ double Bs[16][65];
  const int tid = threadIdx.x;
  const int tx = tid & 15, ty = tid >> 4;
  const int bi = blockIdx.y * 64, bj = blockIdx.x * 64;
  const int li = tid >> 2, lk = (tid & 3) * 4;
  double acc[4][4] = {};
  for (int k0 = 0; k0 < Kd; k0 += 16) {
    int gi = bi + li;
    bool oa = (gi < M);
    const double* pa = A + (size_t)(oa ? gi : 0) * lda + k0 + lk;
    int gj = bj + li;
    bool ob = (gj < N);
    const double* pb = B + (size_t)(ob ? gj : 0) * ldb + k0 + lk;
#pragma unroll
    for (int q = 0; q < 4; ++q) {
      int gk = k0 + lk + q;
      As[lk + q][li] = (oa && gk < Kd) ? pa[q] : 0.0;
      Bs[lk + q][li] = (ob && gk < Kd) ? pb[q] : 0.0;
    }
    __syncthreads();
#pragma unroll
    for (int kk = 0; kk < 16; ++kk) {
      double a[4], bb[4];
#pragma unroll
      for (int u = 0; u < 4; ++u) a[u] = As[kk][ty * 4 + u];
#pragma unroll
      for (int v = 0; v < 4; ++v) bb[v] = Bs[kk][tx * 4 + v];
#pragma unroll
      for (int u = 0; u < 4; ++u)
#pragma unroll
        for (int v = 0; v < 4; ++v) acc[u][v] += a[u] * bb[v];
    }
    __syncthreads();
  }
#pragma unroll
  for (int u = 0; u < 4; ++u) {
    int gi = bi + ty * 4 + u;
    if (gi >= M) continue;
#pragma unroll
    for (int v = 0; v < 4; ++v) {
      int gj = bj + tx * 4 + v;
      if (gj >= N) continue;
      double val = acc[u][v];
      if (ur) val += ur[gi] * vr[gj];
      C[(size_t)gi * ldc + gj] = val;
    }
  }
}

// C = M·M^T (symmetric): only lower-triangular block pairs, mirror write.
__global__ __launch_bounds__(256) void k_syrk(const double* __restrict__ M, double* __restrict__ C, int n, int Kd,
                                              int ld, int ldc) {
  __shared__ double As[16][65];
  __shared__ double Bs[16][65];
  int bid = blockIdx.x;
  int by = 0;
  while ((by + 1) * (by + 2) / 2 <= bid) by++;
  int bx = bid - by * (by + 1) / 2;
  const int tid = threadIdx.x;
  const int tx = tid & 15, ty = tid >> 4;
  const int bi = by * 64, bj = bx * 64;
  const int li = tid >> 2, lk = (tid & 3) * 4;
  double acc[4][4] = {};
  for (int k0 = 0; k0 < Kd; k0 += 16) {
    int gi = bi + li;
    bool oa = (gi < n);
    const double* pa = M + (size_t)(oa ? gi : 0) * ld + k0 + lk;
    int gj = bj + li;
    bool ob = (gj < n);
    const double* pb = M + (size_t)(ob ? gj : 0) * ld + k0 + lk;
#pragma unroll
    for (int q = 0; q < 4; ++q) {
      As[lk + q][li] = oa ? pa[q] : 0.0;
      Bs[lk + q][li] = ob ? pb[q] : 0.0;
    }
    __syncthreads();
#pragma unroll
    for (int kk = 0; kk < 16; ++kk) {
      double a[4], bb[4];
#pragma unroll
      for (int u = 0; u < 4; ++u) a[u] = As[kk][ty * 4 + u];
#pragma unroll
      for (int v = 0; v < 4; ++v) bb[v] = Bs[kk][tx * 4 + v];
#pragma unroll
      for (int u = 0; u < 4; ++u)
#pragma unroll
        for (int v = 0; v < 4; ++v) acc[u][v] += a[u] * bb[v];
    }
    __syncthreads();
  }
#pragma unroll
  for (int u = 0; u < 4; ++u) {
    int gi = bi + ty * 4 + u;
    if (gi >= n) continue;
#pragma unroll
    for (int v = 0; v < 4; ++v) {
      int gj = bj + tx * 4 + v;
      if (gj >= n) continue;
      double val = acc[u][v];
      C[(size_t)gi * ldc + gj] = val;
      if (by > bx) C[(size_t)gj * ldc + gi] = val;
    }
  }
}

// Multi-WG Householder tridiagonalization, TDG WGs x 256 threads, ONE fence-free grid
// barrier per column. A rows are WG-private (normal L2-cached traffic). Cross-WG
// exchange (pvec, orow, vtpp) goes through sc0sc1 atomics only. The single heavyweight
// gbar2 at the co-op->tail handoff makes the bulk A updates visible to WG0.
// (Round-7 negative result: panel-deferred updates ADD serialized latency phases per
// column and regress — the column loop is barrier/latency-bound, not flop-bound.)
__global__ __launch_bounds__(256) void k_tridiag_mw(double* __restrict__ A, int n, double* __restrict__ d,
                                                    double* __restrict__ e, double* __restrict__ tau,
                                                    double* __restrict__ Vrow, double* __restrict__ pvec,
                                                    double* __restrict__ orow, double* __restrict__ vtpp,
                                                    unsigned* __restrict__ flags) {
  __shared__ double vsh[520];
  __shared__ double wsh[520];
  __shared__ double xsh[520];
  __shared__ double redb[4];
  __shared__ double redb2[4];
  __shared__ double bc[1];
  const int tid = threadIdx.x, lane = tid & 63, wid = tid >> 6;
  const int g = blockIdx.x;
  unsigned gen = 0;
  const int ktail = n - 1 - MTAIL;  // first tail iteration (m == MTAIL there)
  // preload x_0 (= row 0, cols 1..) and d[0] redundantly
  double dval = A[0];
  for (int i = tid; i < n - 1; i += 256) xsh[i] = A[1 + i];
  __syncthreads();
  for (int k = 0; k < ktail; ++k) {
    const int m = n - 1 - k;
    const int par = k & 1;
    double* __restrict__ pv = pvec + par * 520;
    double* __restrict__ orw = orow + par * 520;
    double* __restrict__ vt = vtpp + par * 32;
    // ---- phase 1: v, tau redundant from xsh ----
    double part = 0.0;
    for (int i = tid; i < m; i += 256) {
      double xi = xsh[i];
      part += xi * xi;
    }
    part = wred(part);
    if (lane == 0) redb[wid] = part;
    __syncthreads();  // S1: redb ready
    double s2 = redb[0] + redb[1] + redb[2] + redb[3];
    double x0 = xsh[0];
    double tk, v0, alpha;
    if (s2 < 1e-260) {
      tk = 0.0;
      v0 = 0.0;
      alpha = x0;
    } else {
      double sig = sqrt(s2);
      alpha = (x0 >= 0.0) ? -sig : sig;
      v0 = x0 - alpha;
      double vn2 = s2 - x0 * x0 + v0 * v0;
      tk = 2.0 / vn2;
    }
    for (int i = tid; i < m; i += 256) vsh[i] = (i == 0) ? v0 : xsh[i];
    __syncthreads();  // S2: vsh ready (also: everyone done reading redb)
    if (g == 0 && tid == 0) {
      d[k] = dval;
      e[k] = alpha;
      tau[k] = tk;
    }
    {  // distributed Vrow publish (all WGs, disjoint slices; read by later kernels only)
      double* __restrict__ Vr = Vrow + (size_t)k * n;
      for (int i = g * 256 + tid; i < m; i += TDG * 256) Vr[i] = vsh[i];
    }
    // owner of row k+1 publishes its pre-update row (diag + trailing), write-through
    if (((k + 1) & (TDG - 1)) == g) {
      const double* __restrict__ rk1 = A + (size_t)(k + 1) * n + (k + 1);
      for (int j = tid; j < m; j += 256) stg(&orw[j], rk1[j]);
    }
    // ---- matvec p = tk * A * v over owned rows; publish pvec + vtp partial ----
    const int rem = (k + 1) & (TDG - 1);
    const int r0 = (k + 1) + ((g - rem + TDG) & (TDG - 1));
    double vtp = 0.0;
    for (int r = r0 + wid * TDG; r < n; r += 4 * TDG) {
      const int i = r - (k + 1);
      const double* __restrict__ row = A + (size_t)r * n + (k + 1);
      double acc = 0.0;
      for (int j = lane; j < m; j += 64) acc += row[j] * vsh[j];
      acc = wred(acc);
      if (lane == 0) {
        double pi = tk * acc;
        stg(&pv[i], pi);
        vtp += vsh[i] * pi;
      }
    }
    if (lane == 0) redb2[wid] = vtp;
    __syncthreads();
    if (tid == 0) stg(&vt[g], redb2[0] + redb2[1] + redb2[2] + redb2[3]);
    gbarf(flags, gen);  // B: pvec, oldrow, vtpp visible (all went through L3)
    // ---- post-barrier redundant: K0, w, next column, next diag ----
    if (wid == 0) {
      double vv = (lane < TDG) ? ldg_(&vt[lane]) : 0.0;
      vv = wred(vv);
      if (lane == 0) bc[0] = vv;
    }
    __syncthreads();  // bc ready
    const double K0 = 0.5 * tk * bc[0];
    for (int i = tid; i < m; i += 256) wsh[i] = ldg_(&pv[i]) - K0 * vsh[i];
    __syncthreads();  // wsh ready
    const double w0 = wsh[0], vv0 = vsh[0];
    for (int i = tid; i < m - 1; i += 256) xsh[i] = ldg_(&orw[i + 1]) - vsh[i + 1] * w0 - wsh[i + 1] * vv0;
    if (tid == 0) dval = ldg_(&orw[0]) - 2.0 * vv0 * w0;
    // ---- rank-2 update of owned rows (WG-local; normal L2-cached stores) ----
    for (int r = r0 + wid * TDG; r < n; r += 4 * TDG) {
      const int i = r - (k + 1);
      const double vi = vsh[i], wi = wsh[i];
      double* __restrict__ row = A + (size_t)r * n + (k + 1);
      for (int j = lane; j < m; j += 64) row[j] -= vi * wsh[j] + wi * vsh[j];
    }
    __syncthreads();  // iteration boundary: vsh/wsh/xsh stable before reuse
  }
  gbar2(flags, gen);  // heavyweight: all rank-2 updates visible before WG0 reads other WGs' rows
  if (g != 0) return;
  // ---- single-WG tail: k = ktail .. n-3, current column in xsh ----
  for (int k = ktail; k <= n - 3; ++k) {
    const int m = n - 1 - k;
    double part = 0.0;
    for (int i = tid; i < m; i += 256) {
      double xi = xsh[i];
      vsh[i] = xi;
      part += xi * xi;
    }
    part = wred(part);
    if (lane == 0) redb[wid] = part;
    __syncthreads();
    double s2 = redb[0] + redb[1] + redb[2] + redb[3];
    double x0 = vsh[0];
    double tk, v0, alpha;
    if (s2 < 1e-260) {
      tk = 0.0;
      v0 = 0.0;
      alpha = x0;
    } else {
      double sig = sqrt(s2);
      alpha = (x0 >= 0.0) ? -sig : sig;
      v0 = x0 - alpha;
      double vn2 = s2 - x0 * x0 + v0 * v0;
      tk = 2.0 / vn2;
    }
    __syncthreads();
    if (tid == 0) {
      vsh[0] = v0;
      d[k] = A[(size_t)k * n + k];
      e[k] = alpha;
      tau[k] = tk;
    }
    __syncthreads();
    double* __restrict__ Vr = Vrow + (size_t)k * n;
    for (int i = tid; i < m; i += 256) Vr[i] = vsh[i];
    // matvec, wave-per-row
    double vtp = 0.0;
    for (int i = wid; i < m; i += 4) {
      const double* __restrict__ row = A + (size_t)(k + 1 + i) * n + (k + 1);
      double acc = 0.0;
      for (int j = lane; j < m; j += 64) acc += row[j] * vsh[j];
      acc = wred(acc);
      if (lane == 0) {
        double pi = tk * acc;
        wsh[i] = pi;
        vtp += vsh[i] * pi;
      }
    }
    if (lane == 0) redb2[wid] = vtp;
    __syncthreads();
    const double K0 = 0.5 * tk * (redb2[0] + redb2[1] + redb2[2] + redb2[3]);
    for (int i = wid; i < m; i += 4) {
      const double vi = vsh[i];
      const double ci = wsh[i] - 2.0 * K0 * vsh[i];
      double* __restrict__ row = A + (size_t)(k + 1 + i) * n + (k + 1);
      for (int j = lane; j < m; j += 64) {
        double nv = row[j] - (vi * wsh[j] + ci * vsh[j]);
        row[j] = nv;
        if (j == 0 && i >= 1) xsh[i - 1] = nv;
      }
    }
    __syncthreads();
  }
  if (tid == 0) {
    d[n - 2] = A[(size_t)(n - 2) * n + (n - 2)];
    e[n - 2] = A[(size_t)(n - 1) * n + (n - 2)];
    d[n - 1] = A[(size_t)(n - 1) * n + (n - 1)];
  }
}

// Bisection (34 rounds), eigenvalues split across WGs of 64 (one per CU, latency-bound).
__global__ __launch_bounds__(64) void k_bisect_mw(const double* __restrict__ d, const double* __restrict__ e, int n,
                                                  double* __restrict__ lam) {
  __shared__ double ds[520];
  __shared__ double e2s[520];
  __shared__ double bc[4];
  const int tid = threadIdx.x;
  for (int i = tid; i < n; i += 64) {
    ds[i] = d[i];
    e2s[i] = (i >= 1) ? e[i - 1] * e[i - 1] : 0.0;
  }
  __syncthreads();
  if (tid == 0) {
    double glo = 1e300, ghi = -1e300, me2 = 0.0;
    for (int i = 0; i < n; ++i) {
      double ea = (i >= 1) ? sqrt(e2s[i]) : 0.0;
      double eb = (i < n - 1) ? sqrt(e2s[i + 1]) : 0.0;
      glo = fmin(glo, ds[i] - ea - eb);
      ghi = fmax(ghi, ds[i] + ea + eb);
      me2 = fmax(me2, e2s[i]);
    }
    double span = ghi - glo;
    bc[0] = glo - 1e-3 * span - 1e-30;
    bc[1] = ghi + 1e-3 * span + 1e-30;
    bc[2] = fmax(me2 * 2.220446049250313e-16, 1e-280);
  }
  __syncthreads();
  const int idx = blockIdx.x * 64 + tid;
  if (idx < n) {
    double lo = bc[0], hi = bc[1];
    const double pivmin = bc[2];
    for (int r = 0; r < 34; ++r) {
      double x = 0.5 * (lo + hi);
      int cnt = 0;
      double q = ds[0] - x;
      if (q < 0.0) cnt++;
      for (int i = 1; i < n; ++i) {
        double t = q;
        if (fabs(t) < pivmin) t = (t < 0.0) ? -pivmin : pivmin;
        q = (ds[i] - x) - e2s[i] / t;
        if (q < 0.0) cnt++;
      }
      if (cnt <= idx) lo = x;
      else hi = x;
    }
    lam[idx] = 0.5 * (lo + hi);
  }
}

// Spectral readout (identical sequential arithmetic to the old fused tail).
__global__ __launch_bounds__(64) void k_specsum(const double* __restrict__ lam, int n, int keep_start, int step,
                                                float* __restrict__ out, double* __restrict__ scal) {
  if (threadIdx.x == 0) {
    int cnt = 0;
    double st = 0.0, sa = 0.0;
    for (int i = 0; i < n; ++i) {
      double l = lam[i];
      double s = (l > 0.0) ? sqrt(l) : 0.0;
      if (s > 1e-5) cnt++;
      sa += s;
      if (i >= keep_start) st += s;
    }
    bool trunc = (cnt > 321);
    double ssum = trunc ? st : sa;
    const double NORMF = 1448.1546878700494;  // sqrt(4096*512)
    double l1 = ssum / NORMF;
    out[step] = (float)l1;
    scal[S_SCALE] = (l1 > 15.045) ? (15.045 / l1) : 1.0;
  }
}

// Fused: tridiag inverse iteration (thread 0) -> HH chain (1 wave, z in regs, Vrow coalesced)
// -> vhh + g = coef*v^T M + sc (all threads). Steps 2..30 only (n <= 384).
__global__ __launch_bounds__(512) void k_eigvec(const double* __restrict__ Vrow, int n, const double* __restrict__ d,
                                                const double* __restrict__ e, const double* __restrict__ tau,
                                                const double* __restrict__ lam, const double* __restrict__ Mm,
                                                const double* __restrict__ tvec, double* __restrict__ scal,
                                                double* __restrict__ vhh, double* __restrict__ g) {
  __shared__ double zs[384];
  __shared__ double cps[384];
  __shared__ double dsh[384];
  __shared__ double esh[384];
  __shared__ double tsh[384];
  __shared__ double tvsh[384];
  __shared__ double bc[2];
  const int tid = threadIdx.x;
  for (int i = tid; i < n; i += 512) {
    dsh[i] = d[i];
    esh[i] = e[i];
    tsh[i] = tau[i];
    tvsh[i] = tvec[i];
  }
  __syncthreads();
  if (tid == 0) {
    double lmax = fabs(lam[n - 1]);
    double sh = lam[0] - (1e-12 * lmax + 1e-280);
    double me2 = 0.0;
    for (int i = 1; i < n; ++i) {
      double t = esh[i - 1];
      me2 = fmax(me2, t * t);
    }
    double pivmin = fmax(me2 * 2.220446049250313e-16, 1e-280);
    unsigned s = 0xB5297A4Du;
    for (int i = 0; i < n; ++i) {
      s = s * 1664525u + 1013904223u;
      zs[i] = 0.75 + (double)(s >> 8) * (0.5 / 16777216.0);
    }
    for (int it = 0; it < 3; ++it) {
      double den = dsh[0] - sh;
      if (fabs(den) < pivmin) den = (den < 0) ? -pivmin : pivmin;
      cps[0] = esh[0] / den;
      zs[0] = zs[0] / den;
      for (int i = 1; i < n; ++i) {
        den = (dsh[i] - sh) - esh[i - 1] * cps[i - 1];
        if (fabs(den) < pivmin) den = (den < 0) ? -pivmin : pivmin;
        cps[i] = (i < n - 1) ? esh[i] / den : 0.0;
        zs[i] = (zs[i] - esh[i - 1] * zs[i - 1]) / den;
      }
      for (int i = n - 2; i >= 0; --i) zs[i] -= cps[i] * zs[i + 1];
      double nn = 0;
      for (int i = 0; i < n; ++i) nn += zs[i] * zs[i];
      double inv = 1.0 / sqrt(fmax(nn, 1e-300));
      for (int i = 0; i < n; ++i) zs[i] *= inv;
    }
  }
  __syncthreads();
  if (tid < 64) {
    double z[6];
#pragma unroll
    for (int r = 0; r < 6; ++r) {
      int j = tid + 64 * r;
      z[r] = (j < n) ? zs[j] : 0.0;
    }
    for (int k = n - 3; k >= 0; --k) {
      const double tk = tsh[k];
      const double* __restrict__ vr = Vrow + (size_t)k * n;
      double vv[6];
#pragma unroll
      for (int r = 0; r < 6; ++r) {
        int j = tid + 64 * r;
        vv[r] = (j >= k + 1 && j < n) ? vr[j - k - 1] : 0.0;
      }
      double p = 0.0;
#pragma unroll
      for (int r = 0; r < 6; ++r) p += vv[r] * z[r];
      p = wred(p);
      p = __shfl(p, 0, 64);
      double tp = tk * p;
#pragma unroll
      for (int r = 0; r < 6; ++r) z[r] -= tp * vv[r];
    }
    double nn = 0.0;
#pragma unroll
    for (int r = 0; r < 6; ++r) nn += z[r] * z[r];
    nn = wred(nn);
    nn = __shfl(nn, 0, 64);
    double inv = 1.0 / sqrt(fmax(nn, 1e-300));
#pragma unroll
    for (int r = 0; r < 6; ++r) {
      int j = tid + 64 * r;
      if (j < n) zs[j] = z[r] * inv;
    }
  }
  __syncthreads();
  if (tid == 0) {
    double wl = zs[n - 1];
    double sg = (wl >= 0.0) ? 1.0 : -1.0;
    double coef = 1.0 / (1.0 + fabs(wl));  // 2 / (2 + 2|wl|)
    zs[n - 1] = wl + sg;                   // zs now holds vhh
    scal[S_VTV] = 2.0 + 2.0 * fabs(wl);
    bc[0] = coef;
    double sc = 0.0;
    for (int i = 0; i < n; ++i) sc += zs[i] * tvsh[i];
    scal[S_SC] = sc * coef;
  }
  __syncthreads();
  const double coef = bc[0];
  {
    double acc = 0.0;
    for (int i = 0; i < n; ++i) acc += zs[i] * Mm[(size_t)i * DIM + tid];
    g[tid] = coef * acc;
  }
  for (int i = tid; i < n; i += 512) vhh[i] = zs[i];
}

// step-1: inverse iteration for the 321 kept tridiag eigenvectors (one thread each) + neighbor reorth
__global__ __launch_bounds__(512) void k_ii_multi(const double* __restrict__ d, const double* __restrict__ e,
                                                  const double* __restrict__ lam, int n, int keep_start,
                                                  double* __restrict__ Uk, double* __restrict__ cp) {
  const int tid = threadIdx.x, lane = tid & 63, wid = tid >> 6;
  __shared__ double redb[8];
  __shared__ double bc[1];
  if (tid < KEEP) {
    int j = tid;
    double lj = lam[keep_start + j];
    double me2 = 0.0;
    for (int i = 1; i < n; ++i) {
      double t = e[i - 1];
      me2 = fmax(me2, t * t);
    }
    double pivmin = fmax(me2 * 2.220446049250313e-16, 1e-280);
    unsigned s = 0x9E3779B9u * (unsigned)(j + 13);
    for (int i = 0; i < n; ++i) {
      s = s * 1664525u + 1013904223u;
      Uk[(size_t)i * KEEP + j] = 0.5 + (double)(s >> 8) * (1.0 / 16777216.0);
    }
    for (int it = 0; it < 3; ++it) {
      double den = d[0] - lj;
      if (fabs(den) < pivmin) den = (den < 0.0) ? -pivmin : pivmin;
      double cprev = e[0] / den;
      cp[0 * KEEP + j] = cprev;
      double zprev = Uk[0 * KEEP + j] / den;
      Uk[0 * KEEP + j] = zprev;
      for (int i = 1; i < n; ++i) {
        den = (d[i] - lj) - e[i - 1] * cprev;
        if (fabs(den) < pivmin) den = (den < 0.0) ? -pivmin : pivmin;
        double ci = (i < n - 1) ? e[i] / den : 0.0;
        cp[(size_t)i * KEEP + j] = ci;
        double zi = (Uk[(size_t)i * KEEP + j] - e[i - 1] * zprev) / den;
        Uk[(size_t)i * KEEP + j] = zi;
        zprev = zi;
        cprev = ci;
      }
      double zn = Uk[(size_t)(n - 1) * KEEP + j];
      for (int i = n - 2; i >= 0; --i) {
        zn = Uk[(size_t)i * KEEP + j] - cp[(size_t)i * KEEP + j] * zn;
        Uk[(size_t)i * KEEP + j] = zn;
      }
      double nn = 0;
      for (int i = 0; i < n; ++i) {
        double z = Uk[(size_t)i * KEEP + j];
        nn += z * z;
      }
      double inv = 1.0 / sqrt(fmax(nn, 1e-300));
      for (int i = 0; i < n; ++i) Uk[(size_t)i * KEEP + j] *= inv;
    }
  }
  __syncthreads();
  for (int jj = 1; jj < KEEP; ++jj) {
    double l1v = lam[keep_start + jj], l0v = lam[keep_start + jj - 1];
    bool close = (l1v - l0v) < 1e-7 * (fabs(l1v) + 1e-280);
    if (!close) continue;
    double p = 0;
    for (int i = tid; i < n; i += 512) p += Uk[(size_t)i * KEEP + jj] * Uk[(size_t)i * KEEP + jj - 1];
    p = wred(p);
    if (lane == 0) redb[wid] = p;
    __syncthreads();
    if (tid == 0) {
      double s2 = 0;
      for (int q = 0; q < 8; ++q) s2 += redb[q];
      bc[0] = s2;
    }
    __syncthreads();
    double dot = bc[0];
    for (int i = tid; i < n; i += 512) Uk[(size_t)i * KEEP + jj] -= dot * Uk[(size_t)i * KEEP + jj - 1];
    __syncthreads();
    p = 0;
    for (int i = tid; i < n; i += 512) {
      double z = Uk[(size_t)i * KEEP + jj];
      p += z * z;
    }
    p = wred(p);
    if (lane == 0) redb[wid] = p;
    __syncthreads();
    if (tid == 0) {
      double s2 = 0;
      for (int q = 0; q < 8; ++q) s2 += redb[q];
      bc[0] = 1.0 / sqrt(fmax(s2, 1e-300));
    }
    __syncthreads();
    double inv = bc[0];
    for (int i = tid; i < n; i += 512) Uk[(size_t)i * KEEP + jj] *= inv;
    __syncthreads();
  }
}

// apply stored Householder chain (Vrow, coalesced) to each kept eigenvector (one wave per column)
__global__ __launch_bounds__(64) void k_hhapply_multi(const double* __restrict__ Vrow, const double* __restrict__ tau,
                                                      int n, double* __restrict__ Uk) {
  const int j = blockIdx.x;
  const int lane = threadIdx.x;
  for (int k = n - 3; k >= 0; --k) {
    double tk = tau[k];
    if (tk == 0.0) continue;
    int m = n - 1 - k;
    const double* __restrict__ vr = Vrow + (size_t)k * n;
    double p = 0.0;
    for (int i = lane; i < m; i += 64) p += vr[i] * Uk[(size_t)(k + 1 + i) * KEEP + j];
    p = wred(p);
    p = __shfl(p, 0, 64);
    double tp = tk * p;
    for (int i = lane; i < m; i += 64) Uk[(size_t)(k + 1 + i) * KEEP + j] -= tp * vr[i];
  }
  double nn = 0.0;
  for (int i = lane; i < n; i += 64) {
    double z = Uk[(size_t)i * KEEP + j];
    nn += z * z;
  }
  nn = wred(nn);
  nn = __shfl(nn, 0, 64);
  double inv = 1.0 / sqrt(fmax(nn, 1e-300));
  for (int i = lane; i < n; i += 64) Uk[(size_t)i * KEEP + j] *= inv;
}

// C[MxN] = s * A^T·B  where A is Kd x M (lda), B is Kd x N (ldb), s = scal[S_SCALE]
__global__ __launch_bounds__(256) void k_gemm_tn(const double* __restrict__ A, const double* __restrict__ B,
                                                 double* __restrict__ C, int M, int N, int Kd, int lda, int ldb, int ldc,
                                                 const double* __restrict__ scal) {
  __shared__ double As[16][65];
  __shared__ double Bs[16][65];
  const int tid = threadIdx.x;
  const int tx = tid & 15, ty = tid >> 4;
  const int bi = blockIdx.y * 64, bj = blockIdx.x * 64;
  const int li = tid & 63, lq = tid >> 6;
  double acc[4][4] = {};
  for (int k0 = 0; k0 < Kd; k0 += 16) {
#pragma unroll
    for (int q = 0; q < 4; ++q) {
      int kk = lq + q * 4;
      int gk = k0 + kk;
      int gi = bi + li;
      int gj = bj + li;
      As[kk][li] = (gi < M && gk < Kd) ? A[(size_t)gk * lda + gi] : 0.0;
      Bs[kk][li] = (gj < N && gk < Kd) ? B[(size_t)gk * ldb + gj] : 0.0;
    }
    __syncthreads();
#pragma unroll
    for (int kk = 0; kk < 16; ++kk) {
      double a[4], bb[4];
#pragma unroll
      for (int u = 0; u < 4; ++u) a[u] = As[kk][ty * 4 + u];
#pragma unroll
      for (int v = 0; v < 4; ++v) bb[v] = Bs[kk][tx * 4 + v];
#pragma unroll
      for (int u = 0; u < 4; ++u)
#pragma unroll
        for (int v = 0; v < 4; ++v) acc[u][v] += a[u] * bb[v];
    }
    __syncthreads();
  }
  double s = scal[S_SCALE];
#pragma unroll
  for (int u = 0; u < 4; ++u) {
    int gi = bi + ty * 4 + u;
    if (gi >= M) continue;
#pragma unroll
    for (int v = 0; v < 4; ++v) {
      int gj = bj + tx * 4 + v;
      if (gj >= N) continue;
      C[(size_t)gi * ldc + gj] = s * acc[u][v];
    }
  }
}

// c_state = Uk^T tvec
__global__ __launch_bounds__(512) void k_gemv_tn(const double* __restrict__ Uk, const double* __restrict__ tvec,
                                                 double* __restrict__ cstv, int n) {
  int i = threadIdx.x;
  if (i < KEEP) {
    double acc = 0.0;
    for (int k = 0; k < n; ++k) acc += Uk[(size_t)k * KEEP + i] * tvec[k];
    cstv[i] = acc;
  }
}

// C_state = scale*(M - v g^T) rows 0..320 ;  c_state = (tvec - v*sc)[0..320]
__global__ __launch_bounds__(256) void k_hh_update(const double* __restrict__ Mm, const double* __restrict__ vhh,
                                                   const double* __restrict__ g, const double* __restrict__ scal,
                                                   const double* __restrict__ tvec, double* __restrict__ Cst,
                                                   double* __restrict__ cstv) {
  int idx = blockIdx.x * 256 + threadIdx.x;
  double scale = scal[S_SCALE];
  if (idx < KEEP * DIM) {
    int i = idx >> 9, j = idx & 511;
    Cst[(size_t)i * DIM + j] = scale * (Mm[(size_t)i * DIM + j] - vhh[i] * g[j]);
  }
  if (blockIdx.x == 0 && threadIdx.x < KEEP) {
    cstv[threadIdx.x] = tvec[threadIdx.x] - vhh[threadIdx.x] * scal[S_SC];
  }
}

// ---------------- host ----------------

extern "C" void kernel_launch(void* const* d_in, const int* in_sizes, int n_in, void* d_out, int out_size, void* d_ws,
                              size_t ws_size, hipStream_t stream) {
  (void)in_sizes;
  (void)n_in;
  (void)out_size;
  (void)ws_size;
  const float* x = (const float*)d_in[0];
  const float* W = (const float*)d_in[1];
  const float* b = (const float*)d_in[2];
  float* out = (float*)d_out;

  char* ws = (char*)d_ws;
  size_t off = 0;
  auto alloc = [&](size_t nelem) {
    size_t p = off;
    off += (nelem * 8 + 255) & ~(size_t)255;
    return (double*)(ws + p);
  };
  double* Wd = alloc(512 * 512);
  double* bd = alloc(512);
  double* mvec = alloc(512);
  double* Cst = alloc(512 * 512);
  double* cstv = alloc(520);
  double* tvec = alloc(520);
  double* Mm = alloc(513 * 512);
  // Union buffer: Gx (setup, dead after k_chol_mw) -> Aw (per step, dead after k_tridiag_mw)
  // -> cp scratch (step-1 k_ii_multi only, runs after tridiag). Lifetimes strictly disjoint.
  double* AwGx = alloc(513 * 513);
  double* Gx = AwGx;
  double* Aw = AwGx;
  double* zcp = AwGx;
  double* Vrow = alloc(513 * 513);
  double* dT = alloc(520);
  double* eT = alloc(520);
  double* tauT = alloc(520);
  double* lam = alloc(520);
  double* vhh = alloc(520);
  double* gv = alloc(520);
  double* scal = alloc(32);
  double* Uk = alloc(513 * 321);
  // multi-WG shared buffers (pvec/orow/vtpp double-buffered by iteration parity)
  double* pvec = alloc(1040);
  double* orow = alloc(1040);
  double* vtpp = alloc(64);
  unsigned* tflags = (unsigned*)alloc(512);  // 1024 uints, tridiag barrier
  unsigned* cflags = (unsigned*)alloc(512);  // 1024 uints, chol barrier
  // total ~12.0 MB

  // ---- setup ----
  k_cast<<<dim3((512 * 512 + 255) / 256), dim3(256), 0, stream>>>(W, b, Wd, bd, cflags);
  k_colsum<<<dim3(1), dim3(512), 0, stream>>>(x, mvec);
  k_xtx<<<dim3(8, 8), dim3(256), 0, stream>>>(x, Gx);
  k_chol_mw<<<dim3(TDG), dim3(256), 0, stream>>>(Gx, Cst, cflags);
  k_solvec0<<<dim3(1), dim3(64), 0, stream>>>(Cst, mvec, cstv);

  // ---- step 1 (r=512, n=513) ----
  {
    const int r = 512, n = 513;
    k_prep<<<dim3(1), dim3(512), 0, stream>>>(cstv, bd, r, tvec, Mm, scal, tflags);
    k_gemm_nt<<<dim3(8, 8), dim3(256), 0, stream>>>(Cst, Wd, Mm, r, 512, 512, 512, 512, 512, cstv, bd);
    k_syrk<<<dim3(45), dim3(256), 0, stream>>>(Mm, Aw, n, 512, 512, n);
    k_tridiag_mw<<<dim3(TDG), dim3(256), 0, stream>>>(Aw, n, dT, eT, tauT, Vrow, pvec, orow, vtpp, tflags);
    k_bisect_mw<<<dim3((n + 63) / 64), dim3(64), 0, stream>>>(dT, eT, n, lam);
    k_specsum<<<dim3(1), dim3(64), 0, stream>>>(lam, n, n - KEEP, 0, out, scal);
    k_ii_multi<<<dim3(1), dim3(512), 0, stream>>>(dT, eT, lam, n, n - KEEP, Uk, zcp);
    k_hhapply_multi<<<dim3(KEEP), dim3(64), 0, stream>>>(Vrow, tauT, n, Uk);
    k_gemm_tn<<<dim3(8, 6), dim3(256), 0, stream>>>(Uk, Mm, Cst, KEEP, 512, n, KEEP, 512, 512, scal);
    k_gemv_tn<<<dim3(1), dim3(512), 0, stream>>>(Uk, tvec, cstv, n);
  }

  // ---- steps 2..30 (r=321, n=322) ----
  for (int t = 1; t < NSTEPS; ++t) {
    const int r = KEEP, n = KEEP + 1;
    k_prep<<<dim3(1), dim3(512), 0, stream>>>(cstv, bd, r, tvec, Mm, scal, tflags);
    k_gemm_nt<<<dim3(8, 6), dim3(256), 0, stream>>>(Cst, Wd, Mm, r, 512, 512, 512, 512, 512, cstv, bd);
    k_syrk<<<dim3(21), dim3(256), 0, stream>>>(Mm, Aw, n, 512, 512, n);
    k_tridiag_mw<<<dim3(TDG), dim3(256), 0, stream>>>(Aw, n, dT, eT, tauT, Vrow, pvec, orow, vtpp, tflags);
    k_bisect_mw<<<dim3((n + 63) / 64), dim3(64), 0, stream>>>(dT, eT, n, lam);
    k_specsum<<<dim3(1), dim3(64), 0, stream>>>(lam, n, 1, t, out, scal);
    k_eigvec<<<dim3(1), dim3(512), 0, stream>>>(Vrow, n, dT, eT, tauT, lam, Mm, tvec, scal, vhh, gv);
    k_hh_update<<<dim3((KEEP * DIM + 255) / 256), dim3(256), 0, stream>>>(Mm, vhh, gv, scal, tvec, Cst, cstv);
  }
}

// Round 9
// 106266.602 us; speedup vs baseline: 1.7369x; 1.3614x over previous
//
#include <hip/hip_runtime.h>
#include <math.h>

#define DIM 512
#define BATCH 4096
#define NSTEPS 30
#define KEEP 321

#define S_BETA 0
#define S_SCALE 1
#define S_VTV 4
#define S_SC 5

#define TDG 32    // workgroups cooperating in k_tridiag_mw / k_chol_mw
#define MTAIL 96  // tridiag: below this trailing size, WG0 finishes alone (round-4 verified value)

__device__ __forceinline__ double wred(double v) {
#pragma unroll
  for (int o = 32; o > 0; o >>= 1) v += __shfl_down(v, (unsigned)o, 64);
  return v;
}

// Agent-scope (device) relaxed atomics: sc0|sc1 accesses that write-through / read-through
// the die-level coherence point. No L2 writeback/invalidate involved.
__device__ __forceinline__ void stg(double* p, double v) {
  __hip_atomic_store(p, v, __ATOMIC_RELAXED, __HIP_MEMORY_SCOPE_AGENT);
}
__device__ __forceinline__ double ldg_(const double* p) {
  return __hip_atomic_load(p, __ATOMIC_RELAXED, __HIP_MEMORY_SCOPE_AGENT);
}

// Heavyweight grid barrier (full agent fences) — ONLY where bulk L2-cached data must
// become visible across WGs (co-op -> tail handoff in tridiag).
__device__ __forceinline__ void gbar2(unsigned* __restrict__ flags, unsigned& gen) {
  gen++;
  const unsigned target = gen;
  __syncthreads();
  if (threadIdx.x == 0) {
    __threadfence();
    __hip_atomic_store(flags + (size_t)blockIdx.x * 32, target, __ATOMIC_RELAXED, __HIP_MEMORY_SCOPE_AGENT);
  }
  if (threadIdx.x < 64) {
    bool ok = ((int)threadIdx.x >= TDG);
    while (!__all(ok)) {
      if (!ok) {
        unsigned v = __hip_atomic_load(flags + (size_t)threadIdx.x * 32, __ATOMIC_RELAXED, __HIP_MEMORY_SCOPE_AGENT);
        ok = (v >= target);
      }
    }
    __threadfence();
  }
  __syncthreads();
}

// Fence-free grid barrier: all cross-WG data goes through stg/ldg_ (sc0sc1).
__device__ __forceinline__ void gbarf(unsigned* __restrict__ flags, unsigned& gen) {
  gen++;
  const unsigned target = gen;
  __syncthreads();
  if (threadIdx.x == 0) {
    __hip_atomic_store(flags + (size_t)blockIdx.x * 32, target, __ATOMIC_RELAXED, __HIP_MEMORY_SCOPE_AGENT);
  }
  if (threadIdx.x < 64) {
    bool ok = ((int)threadIdx.x >= TDG);
    while (!__all(ok)) {
      if (!ok) {
        unsigned v = __hip_atomic_load(flags + (size_t)threadIdx.x * 32, __ATOMIC_RELAXED, __HIP_MEMORY_SCOPE_AGENT);
        ok = (v >= target);
      }
    }
    asm volatile("" ::: "memory");
  }
  __syncthreads();
}

// ---------------- setup kernels ----------------

__global__ __launch_bounds__(256) void k_cast(const float* __restrict__ W, const float* __restrict__ b,
                                              double* __restrict__ Wd, double* __restrict__ bd,
                                              unsigned* __restrict__ cflags) {
  int idx = blockIdx.x * 256 + threadIdx.x;
  if (idx < DIM * DIM) Wd[idx] = (double)W[idx];
  if (idx < DIM) bd[idx] = (double)b[idx];
  if (blockIdx.x == 0) {
    for (int i = threadIdx.x; i < 1024; i += 256) cflags[i] = 0;
  }
}

__global__ __launch_bounds__(512) void k_colsum(const float* __restrict__ x, double* __restrict__ mvec) {
  int j = threadIdx.x;
  double s = 0.0;
  for (int r = 0; r < BATCH; ++r) s += (double)x[(size_t)r * DIM + j];
  mvec[j] = s;
}

// Gx = x^T x in fp64 (x fp32).
__global__ __launch_bounds__(256) void k_xtx(const float* __restrict__ x, double* __restrict__ Gx) {
  __shared__ double As[16][65];
  __shared__ double Bs[16][65];
  const int tid = threadIdx.x;
  const int tx = tid & 15, ty = tid >> 4;
  const int bi = blockIdx.y * 64, bj = blockIdx.x * 64;
  const int lr = tid >> 4, lc4 = (tid & 15) * 4;
  double acc[4][4] = {};
  for (int r0 = 0; r0 < BATCH; r0 += 16) {
#pragma unroll
    for (int q = 0; q < 4; ++q) {
      As[lr][lc4 + q] = (double)x[(size_t)(r0 + lr) * DIM + bi + lc4 + q];
      Bs[lr][lc4 + q] = (double)x[(size_t)(r0 + lr) * DIM + bj + lc4 + q];
    }
    __syncthreads();
#pragma unroll
    for (int rr = 0; rr < 16; ++rr) {
      double a[4], bb[4];
#pragma unroll
      for (int u = 0; u < 4; ++u) a[u] = As[rr][ty * 4 + u];
#pragma unroll
      for (int v = 0; v < 4; ++v) bb[v] = Bs[rr][tx * 4 + v];
#pragma unroll
      for (int u = 0; u < 4; ++u)
#pragma unroll
        for (int v = 0; v < 4; ++v) acc[u][v] += a[u] * bb[v];
    }
    __syncthreads();
  }
#pragma unroll
  for (int u = 0; u < 4; ++u)
#pragma unroll
    for (int v = 0; v < 4; ++v) Gx[(size_t)(bi + ty * 4 + u) * DIM + bj + tx * 4 + v] = acc[u][v];
}

// Multi-WG Cholesky Gx = R^T R (R upper, lower zeroed), TDG WGs.
__global__ __launch_bounds__(256) void k_chol_mw(const double* __restrict__ G, double* __restrict__ R,
                                                 unsigned* __restrict__ flags) {
  __shared__ double Lr[16][512];
  __shared__ double rowk[512];
  const int tid = threadIdx.x, lane = tid & 63, wid = tid >> 6;
  const int g = blockIdx.x;
  unsigned gen = 0;
  for (int s = 0; s < 16; ++s) {
    const int i = s * 32 + g;
    for (int j = tid; j < DIM; j += 256) Lr[s][j] = G[(size_t)i * DIM + j];
  }
  __syncthreads();
  for (int k = 0; k < DIM; ++k) {
    if ((k & 31) == g) {
      const int s = k >> 5;
      double dkk = Lr[s][k];
      double sq = sqrt(fmax(dkk, 1e-280));
      double inv = 1.0 / sq;
      for (int j = tid; j < DIM; j += 256) {
        double v;
        if (j < k) v = 0.0;
        else if (j == k) v = sq;
        else v = Lr[s][j] * inv;
        stg(&R[(size_t)k * DIM + j], v);
      }
    }
    gbarf(flags, gen);
    for (int j = k + tid; j < DIM; j += 256) rowk[j] = ldg_(&R[(size_t)k * DIM + j]);
    __syncthreads();
    for (int s = wid; s < 16; s += 4) {
      const int i = s * 32 + g;
      if (i <= k) continue;
      const double rki = rowk[i];
      for (int j = i + lane; j < DIM; j += 64) Lr[s][j] -= rki * rowk[j];
    }
    __syncthreads();
  }
}

// forward-substitution R^T c0 = mvec — single wave, rhs in registers, no barriers
__global__ __launch_bounds__(64) void k_solvec0(const double* __restrict__ R, const double* __restrict__ mvec,
                                                double* __restrict__ c0) {
  const int lane = threadIdx.x;
  double rhs[8], cs[8];
#pragma unroll
  for (int r = 0; r < 8; ++r) rhs[r] = mvec[lane + 64 * r];
#pragma unroll
  for (int r = 0; r < 8; ++r) cs[r] = 0.0;
  for (int i = 0; i < DIM; ++i) {
    int owner = i & 63, ri = i >> 6;
    double ci = 0.0;
    if (lane == owner) {
      ci = rhs[ri] / R[(size_t)i * DIM + i];
      cs[ri] = ci;
    }
    ci = __shfl(ci, owner, 64);
    const double* row = R + (size_t)i * DIM;
#pragma unroll
    for (int r = 0; r < 8; ++r) {
      int j = lane + 64 * r;
      if (j > i) rhs[r] -= ci * row[j];
    }
  }
#pragma unroll
  for (int r = 0; r < 8; ++r) c0[lane + 64 * r] = cs[r];
}

// ---------------- per-step kernels ----------------

__global__ __launch_bounds__(512) void k_prep(const double* __restrict__ cstv, const double* __restrict__ bd, int r,
                                              double* __restrict__ tvec, double* __restrict__ Mm,
                                              double* __restrict__ scal, unsigned* __restrict__ tflags) {
  __shared__ double redb[8];
  __shared__ double bc[1];
  const int tid = threadIdx.x, lane = tid & 63, wid = tid >> 6;
  for (int i = tid; i < 1024; i += 512) tflags[i] = 0;  // reset tridiag barrier flags
  double p = 0.0;
  for (int i = tid; i < r; i += 512) {
    double c = cstv[i];
    p += c * c;
    tvec[i] = c;
  }
  p = wred(p);
  if (lane == 0) redb[wid] = p;
  __syncthreads();
  if (tid == 0) {
    double s = 0;
    for (int q = 0; q < 8; ++q) s += redb[q];
    double beta = sqrt(fmax(4096.0 - s, 1e-20));
    tvec[r] = beta;
    scal[S_BETA] = beta;
    bc[0] = beta;
  }
  __syncthreads();
  double beta = bc[0];
  for (int j = tid; j < DIM; j += 512) Mm[(size_t)r * DIM + j] = beta * bd[j];
}

// C[MxN] = A·B^T (+ ur·vr^T), row-major, fp64.
__global__ __launch_bounds__(256) void k_gemm_nt(const double* __restrict__ A, const double* __restrict__ B,
                                                 double* __restrict__ C, int M, int N, int Kd, int lda, int ldb, int ldc,
                                                 const double* __restrict__ ur, const double* __restrict__ vr) {
  __shared__ double As[16][65];
  __shared__ double Bs[16][65];
  const int tid = threadIdx.x;
  const int tx = tid & 15, ty = tid >> 4;
  const int bi = blockIdx.y * 64, bj = blockIdx.x * 64;
  const int li = tid >> 2, lk = (tid & 3) * 4;
  double acc[4][4] = {};
  for (int k0 = 0; k0 < Kd; k0 += 16) {
    int gi = bi + li;
    bool oa = (gi < M);
    const double* pa = A + (size_t)(oa ? gi : 0) * lda + k0 + lk;
    int gj = bj + li;
    bool ob = (gj < N);
    const double* pb = B + (size_t)(ob ? gj : 0) * ldb + k0 + lk;
#pragma unroll
    for (int q = 0; q < 4; ++q) {
      int gk = k0 + lk + q;
      As[lk + q][li] = (oa && gk < Kd) ? pa[q] : 0.0;
      Bs[lk + q][li] = (ob && gk < Kd) ? pb[q] : 0.0;
    }
    __syncthreads();
#pragma unroll
    for (int kk = 0; kk < 16; ++kk) {
      double a[4], bb[4];
#pragma unroll
      for (int u = 0; u < 4; ++u) a[u] = As[kk][ty * 4 + u];
#pragma unroll
      for (int v = 0; v < 4; ++v) bb[v] = Bs[kk][tx * 4 + v];
#pragma unroll
      for (int u = 0; u < 4; ++u)
#pragma unroll
        for (int v = 0; v < 4; ++v) acc[u][v] += a[u] * bb[v];
    }
    __syncthreads();
  }
#pragma unroll
  for (int u = 0; u < 4; ++u) {
    int gi = bi + ty * 4 + u;
    if (gi >= M) continue;
#pragma unroll
    for (int v = 0; v < 4; ++v) {
      int gj = bj + tx * 4 + v;
      if (gj >= N) continue;
      double val = acc[u][v];
      if (ur) val += ur[gi] * vr[gj];
      C[(size_t)gi * ldc + gj] = val;
    }
  }
}

// C = M·M^T (symmetric): only lower-triangular block pairs, mirror write.
__global__ __launch_bounds__(256) void k_syrk(const double* __restrict__ M, double* __restrict__ C, int n, int Kd,
                                              int ld, int ldc) {
  __shared__ double As[16][65];
  __shared__ double Bs[16][65];
  int bid = blockIdx.x;
  int by = 0;
  while ((by + 1) * (by + 2) / 2 <= bid) by++;
  int bx = bid - by * (by + 1) / 2;
  const int tid = threadIdx.x;
  const int tx = tid & 15, ty = tid >> 4;
  const int bi = by * 64, bj = bx * 64;
  const int li = tid >> 2, lk = (tid & 3) * 4;
  double acc[4][4] = {};
  for (int k0 = 0; k0 < Kd; k0 += 16) {
    int gi = bi + li;
    bool oa = (gi < n);
    const double* pa = M + (size_t)(oa ? gi : 0) * ld + k0 + lk;
    int gj = bj + li;
    bool ob = (gj < n);
    const double* pb = M + (size_t)(ob ? gj : 0) * ld + k0 + lk;
#pragma unroll
    for (int q = 0; q < 4; ++q) {
      As[lk + q][li] = oa ? pa[q] : 0.0;
      Bs[lk + q][li] = ob ? pb[q] : 0.0;
    }
    __syncthreads();
#pragma unroll
    for (int kk = 0; kk < 16; ++kk) {
      double a[4], bb[4];
#pragma unroll
      for (int u = 0; u < 4; ++u) a[u] = As[kk][ty * 4 + u];
#pragma unroll
      for (int v = 0; v < 4; ++v) bb[v] = Bs[kk][tx * 4 + v];
#pragma unroll
      for (int u = 0; u < 4; ++u)
#pragma unroll
        for (int v = 0; v < 4; ++v) acc[u][v] += a[u] * bb[v];
    }
    __syncthreads();
  }
#pragma unroll
  for (int u = 0; u < 4; ++u) {
    int gi = bi + ty * 4 + u;
    if (gi >= n) continue;
#pragma unroll
    for (int v = 0; v < 4; ++v) {
      int gj = bj + tx * 4 + v;
      if (gj >= n) continue;
      double val = acc[u][v];
      C[(size_t)gi * ldc + gj] = val;
      if (by > bx) C[(size_t)gj * ldc + gi] = val;
    }
  }
}

// Multi-WG Householder tridiagonalization, TDG WGs x 256 threads, ONE fence-free grid
// barrier per column. A rows are WG-private (normal L2-cached traffic). Cross-WG
// exchange (pvec, orow, vtpp) goes through sc0sc1 atomics only. The single heavyweight
// gbar2 at the co-op->tail handoff makes the bulk A updates visible to WG0.
// Post-barrier: wsh and xsh built in ONE fused pass (overlapped pv/orow L3 reads).
__global__ __launch_bounds__(256) void k_tridiag_mw(double* __restrict__ A, int n, double* __restrict__ d,
                                                    double* __restrict__ e, double* __restrict__ tau,
                                                    double* __restrict__ Vrow, double* __restrict__ pvec,
                                                    double* __restrict__ orow, double* __restrict__ vtpp,
                                                    unsigned* __restrict__ flags) {
  __shared__ double vsh[520];
  __shared__ double wsh[520];
  __shared__ double xsh[520];
  __shared__ double redb[4];
  __shared__ double redb2[4];
  __shared__ double bc[1];
  const int tid = threadIdx.x, lane = tid & 63, wid = tid >> 6;
  const int g = blockIdx.x;
  unsigned gen = 0;
  const int ktail = n - 1 - MTAIL;  // first tail iteration (m == MTAIL there)
  // preload x_0 (= row 0, cols 1..) and d[0] redundantly
  double dval = A[0];
  for (int i = tid; i < n - 1; i += 256) xsh[i] = A[1 + i];
  __syncthreads();
  for (int k = 0; k < ktail; ++k) {
    const int m = n - 1 - k;
    const int par = k & 1;
    double* __restrict__ pv = pvec + par * 520;
    double* __restrict__ orw = orow + par * 520;
    double* __restrict__ vt = vtpp + par * 32;
    // ---- phase 1: v, tau redundant from xsh ----
    double part = 0.0;
    for (int i = tid; i < m; i += 256) {
      double xi = xsh[i];
      part += xi * xi;
    }
    part = wred(part);
    if (lane == 0) redb[wid] = part;
    __syncthreads();  // S1: redb ready
    double s2 = redb[0] + redb[1] + redb[2] + redb[3];
    double x0 = xsh[0];
    double tk, v0, alpha;
    if (s2 < 1e-260) {
      tk = 0.0;
      v0 = 0.0;
      alpha = x0;
    } else {
      double sig = sqrt(s2);
      alpha = (x0 >= 0.0) ? -sig : sig;
      v0 = x0 - alpha;
      double vn2 = s2 - x0 * x0 + v0 * v0;
      tk = 2.0 / vn2;
    }
    for (int i = tid; i < m; i += 256) vsh[i] = (i == 0) ? v0 : xsh[i];
    __syncthreads();  // S2: vsh ready (also: everyone done reading redb)
    if (g == 0 && tid == 0) {
      d[k] = dval;
      e[k] = alpha;
      tau[k] = tk;
    }
    {  // distributed Vrow publish (all WGs, disjoint slices; read by later kernels only)
      double* __restrict__ Vr = Vrow + (size_t)k * n;
      for (int i = g * 256 + tid; i < m; i += TDG * 256) Vr[i] = vsh[i];
    }
    // owner of row k+1 publishes its pre-update row (diag + trailing), write-through
    if (((k + 1) & (TDG - 1)) == g) {
      const double* __restrict__ rk1 = A + (size_t)(k + 1) * n + (k + 1);
      for (int j = tid; j < m; j += 256) stg(&orw[j], rk1[j]);
    }
    // ---- matvec p = tk * A * v over owned rows; publish pvec + vtp partial ----
    const int rem = (k + 1) & (TDG - 1);
    const int r0 = (k + 1) + ((g - rem + TDG) & (TDG - 1));
    double vtp = 0.0;
    for (int r = r0 + wid * TDG; r < n; r += 4 * TDG) {
      const int i = r - (k + 1);
      const double* __restrict__ row = A + (size_t)r * n + (k + 1);
      double acc = 0.0;
      for (int j = lane; j < m; j += 64) acc += row[j] * vsh[j];
      acc = wred(acc);
      if (lane == 0) {
        double pi = tk * acc;
        stg(&pv[i], pi);
        vtp += vsh[i] * pi;
      }
    }
    if (lane == 0) redb2[wid] = vtp;
    __syncthreads();
    if (tid == 0) stg(&vt[g], redb2[0] + redb2[1] + redb2[2] + redb2[3]);
    gbarf(flags, gen);  // B: pvec, oldrow, vtpp visible (all went through L3)
    // ---- post-barrier redundant: K0, fused {w, next column}, next diag ----
    if (wid == 0) {
      double vv = (lane < TDG) ? ldg_(&vt[lane]) : 0.0;
      vv = wred(vv);
      if (lane == 0) bc[0] = vv;
    }
    __syncthreads();  // bc ready
    const double K0 = 0.5 * tk * bc[0];
    const double vv0 = vsh[0];
    const double w0 = ldg_(&pv[0]) - K0 * vv0;  // identical in every thread (broadcast L3 line)
    for (int i = tid; i < m; i += 256) {
      double w = ldg_(&pv[i]) - K0 * vsh[i];
      wsh[i] = w;
      if (i >= 1) xsh[i - 1] = ldg_(&orw[i]) - vsh[i] * w0 - w * vv0;
    }
    if (tid == 0) dval = ldg_(&orw[0]) - 2.0 * vv0 * w0;
    __syncthreads();  // wsh & xsh ready
    // ---- rank-2 update of owned rows (WG-local; normal L2-cached stores) ----
    for (int r = r0 + wid * TDG; r < n; r += 4 * TDG) {
      const int i = r - (k + 1);
      const double vi = vsh[i], wi = wsh[i];
      double* __restrict__ row = A + (size_t)r * n + (k + 1);
      for (int j = lane; j < m; j += 64) row[j] -= vi * wsh[j] + wi * vsh[j];
    }
    __syncthreads();  // iteration boundary: vsh/wsh/xsh stable before reuse
  }
  gbar2(flags, gen);  // heavyweight: all rank-2 updates visible before WG0 reads other WGs' rows
  if (g != 0) return;
  // ---- single-WG tail: k = ktail .. n-3, current column in xsh ----
  for (int k = ktail; k <= n - 3; ++k) {
    const int m = n - 1 - k;
    double part = 0.0;
    for (int i = tid; i < m; i += 256) {
      double xi = xsh[i];
      vsh[i] = xi;
      part += xi * xi;
    }
    part = wred(part);
    if (lane == 0) redb[wid] = part;
    __syncthreads();
    double s2 = redb[0] + redb[1] + redb[2] + redb[3];
    double x0 = vsh[0];
    double tk, v0, alpha;
    if (s2 < 1e-260) {
      tk = 0.0;
      v0 = 0.0;
      alpha = x0;
    } else {
      double sig = sqrt(s2);
      alpha = (x0 >= 0.0) ? -sig : sig;
      v0 = x0 - alpha;
      double vn2 = s2 - x0 * x0 + v0 * v0;
      tk = 2.0 / vn2;
    }
    __syncthreads();
    if (tid == 0) {
      vsh[0] = v0;
      d[k] = A[(size_t)k * n + k];
      e[k] = alpha;
      tau[k] = tk;
    }
    __syncthreads();
    double* __restrict__ Vr = Vrow + (size_t)k * n;
    for (int i = tid; i < m; i += 256) Vr[i] = vsh[i];
    // matvec, wave-per-row
    double vtp = 0.0;
    for (int i = wid; i < m; i += 4) {
      const double* __restrict__ row = A + (size_t)(k + 1 + i) * n + (k + 1);
      double acc = 0.0;
      for (int j = lane; j < m; j += 64) acc += row[j] * vsh[j];
      acc = wred(acc);
      if (lane == 0) {
        double pi = tk * acc;
        wsh[i] = pi;
        vtp += vsh[i] * pi;
      }
    }
    if (lane == 0) redb2[wid] = vtp;
    __syncthreads();
    const double K0 = 0.5 * tk * (redb2[0] + redb2[1] + redb2[2] + redb2[3]);
    for (int i = wid; i < m; i += 4) {
      const double vi = vsh[i];
      const double ci = wsh[i] - 2.0 * K0 * vsh[i];
      double* __restrict__ row = A + (size_t)(k + 1 + i) * n + (k + 1);
      for (int j = lane; j < m; j += 64) {
        double nv = row[j] - (vi * wsh[j] + ci * vsh[j]);
        row[j] = nv;
        if (j == 0 && i >= 1) xsh[i - 1] = nv;
      }
    }
    __syncthreads();
  }
  if (tid == 0) {
    d[n - 2] = A[(size_t)(n - 2) * n + (n - 2)];
    e[n - 2] = A[(size_t)(n - 1) * n + (n - 2)];
    d[n - 1] = A[(size_t)(n - 1) * n + (n - 1)];
  }
}

// 65-section multisection eigensolve: ONE WAVE PER EIGENVALUE; the 64 lanes probe 64
// distinct x per round (independent Sturm chains in lockstep), ballot+popc picks the
// bracket (Sturm count monotone in x => ok-mask is a lane prefix). 7 rounds shrink the
// span by 65^7 ~ 4.9e12 (> the old 2^34), at 7/34 of the dependent-chain length.
__global__ __launch_bounds__(64) void k_bisect_ms(const double* __restrict__ d, const double* __restrict__ e, int n,
                                                  double* __restrict__ lam) {
  __shared__ double ds[520];
  __shared__ double e2s[520];
  const int lane = threadIdx.x;
  const int ev = blockIdx.x;
  for (int i = lane; i < n; i += 64) {
    ds[i] = d[i];
    e2s[i] = (i >= 1) ? e[i - 1] * e[i - 1] : 0.0;
  }
  __syncthreads();
  // Gershgorin bounds + pivmin, wave-parallel
  double glo = 1e300, ghi = -1e300, me2 = 0.0;
  for (int i = lane; i < n; i += 64) {
    double ea = (i >= 1) ? sqrt(e2s[i]) : 0.0;
    double eb = (i < n - 1) ? sqrt(e2s[i + 1]) : 0.0;
    glo = fmin(glo, ds[i] - ea - eb);
    ghi = fmax(ghi, ds[i] + ea + eb);
    me2 = fmax(me2, e2s[i]);
  }
#pragma unroll
  for (int o = 32; o > 0; o >>= 1) {
    glo = fmin(glo, __shfl_down(glo, (unsigned)o, 64));
    ghi = fmax(ghi, __shfl_down(ghi, (unsigned)o, 64));
    me2 = fmax(me2, __shfl_down(me2, (unsigned)o, 64));
  }
  glo = __shfl(glo, 0, 64);
  ghi = __shfl(ghi, 0, 64);
  me2 = __shfl(me2, 0, 64);
  double span = ghi - glo;
  double lo = glo - 1e-3 * span - 1e-30;
  double hi = ghi + 1e-3 * span + 1e-30;
  const double pivmin = fmax(me2 * 2.220446049250313e-16, 1e-280);
  for (int r = 0; r < 7; ++r) {
    const double x = lo + (hi - lo) * ((double)(lane + 1) * (1.0 / 65.0));
    int cnt = 0;
    double q = ds[0] - x;
    if (q < 0.0) cnt++;
    for (int i = 1; i < n; ++i) {
      double t = q;
      if (fabs(t) < pivmin) t = (t < 0.0) ? -pivmin : pivmin;
      q = (ds[i] - x) - e2s[i] / t;
      if (q < 0.0) cnt++;
    }
    unsigned long long mask = __ballot(cnt <= ev);
    int pc = (int)__popcll(mask);
    double nlo = (pc > 0) ? __shfl(x, pc - 1, 64) : lo;
    double nhi = (pc < 64) ? __shfl(x, pc, 64) : hi;
    lo = nlo;
    hi = nhi;
  }
  if (lane == 0) lam[ev] = 0.5 * (lo + hi);
}

// Spectral readout (identical sequential arithmetic).
__global__ __launch_bounds__(64) void k_specsum(const double* __restrict__ lam, int n, int keep_start, int step,
                                                float* __restrict__ out, double* __restrict__ scal) {
  if (threadIdx.x == 0) {
    int cnt = 0;
    double st = 0.0, sa = 0.0;
    for (int i = 0; i < n; ++i) {
      double l = lam[i];
      double s = (l > 0.0) ? sqrt(l) : 0.0;
      if (s > 1e-5) cnt++;
      sa += s;
      if (i >= keep_start) st += s;
    }
    bool trunc = (cnt > 321);
    double ssum = trunc ? st : sa;
    const double NORMF = 1448.1546878700494;  // sqrt(4096*512)
    double l1 = ssum / NORMF;
    out[step] = (float)l1;
    scal[S_SCALE] = (l1 > 15.045) ? (15.045 / l1) : 1.0;
  }
}

// Fused: tridiag inverse iteration (thread 0) -> HH chain (1 wave, z in regs, Vrow coalesced)
// -> vhh + g = coef*v^T M + sc (all threads). Steps 2..30 only (n <= 384).
__global__ __launch_bounds__(512) void k_eigvec(const double* __restrict__ Vrow, int n, const double* __restrict__ d,
                                                const double* __restrict__ e, const double* __restrict__ tau,
                                                const double* __restrict__ lam, const double* __restrict__ Mm,
                                                const double* __restrict__ tvec, double* __restrict__ scal,
                                                double* __restrict__ vhh, double* __restrict__ g) {
  __shared__ double zs[384];
  __shared__ double cps[384];
  __shared__ double dsh[384];
  __shared__ double esh[384];
  __shared__ double tsh[384];
  __shared__ double tvsh[384];
  __shared__ double bc[2];
  const int tid = threadIdx.x;
  for (int i = tid; i < n; i += 512) {
    dsh[i] = d[i];
    esh[i] = e[i];
    tsh[i] = tau[i];
    tvsh[i] = tvec[i];
  }
  __syncthreads();
  if (tid == 0) {
    double lmax = fabs(lam[n - 1]);
    double sh = lam[0] - (1e-12 * lmax + 1e-280);
    double me2 = 0.0;
    for (int i = 1; i < n; ++i) {
      double t = esh[i - 1];
      me2 = fmax(me2, t * t);
    }
    double pivmin = fmax(me2 * 2.220446049250313e-16, 1e-280);
    unsigned s = 0xB5297A4Du;
    for (int i = 0; i < n; ++i) {
      s = s * 1664525u + 1013904223u;
      zs[i] = 0.75 + (double)(s >> 8) * (0.5 / 16777216.0);
    }
    for (int it = 0; it < 3; ++it) {
      double den = dsh[0] - sh;
      if (fabs(den) < pivmin) den = (den < 0) ? -pivmin : pivmin;
      cps[0] = esh[0] / den;
      zs[0] = zs[0] / den;
      for (int i = 1; i < n; ++i) {
        den = (dsh[i] - sh) - esh[i - 1] * cps[i - 1];
        if (fabs(den) < pivmin) den = (den < 0) ? -pivmin : pivmin;
        cps[i] = (i < n - 1) ? esh[i] / den : 0.0;
        zs[i] = (zs[i] - esh[i - 1] * zs[i - 1]) / den;
      }
      for (int i = n - 2; i >= 0; --i) zs[i] -= cps[i] * zs[i + 1];
      double nn = 0;
      for (int i = 0; i < n; ++i) nn += zs[i] * zs[i];
      double inv = 1.0 / sqrt(fmax(nn, 1e-300));
      for (int i = 0; i < n; ++i) zs[i] *= inv;
    }
  }
  __syncthreads();
  if (tid < 64) {
    double z[6];
#pragma unroll
    for (int r = 0; r < 6; ++r) {
      int j = tid + 64 * r;
      z[r] = (j < n) ? zs[j] : 0.0;
    }
    for (int k = n - 3; k >= 0; --k) {
      const double tk = tsh[k];
      const double* __restrict__ vr = Vrow + (size_t)k * n;
      double vv[6];
#pragma unroll
      for (int r = 0; r < 6; ++r) {
        int j = tid + 64 * r;
        vv[r] = (j >= k + 1 && j < n) ? vr[j - k - 1] : 0.0;
      }
      double p = 0.0;
#pragma unroll
      for (int r = 0; r < 6; ++r) p += vv[r] * z[r];
      p = wred(p);
      p = __shfl(p, 0, 64);
      double tp = tk * p;
#pragma unroll
      for (int r = 0; r < 6; ++r) z[r] -= tp * vv[r];
    }
    double nn = 0.0;
#pragma unroll
    for (int r = 0; r < 6; ++r) nn += z[r] * z[r];
    nn = wred(nn);
    nn = __shfl(nn, 0, 64);
    double inv = 1.0 / sqrt(fmax(nn, 1e-300));
#pragma unroll
    for (int r = 0; r < 6; ++r) {
      int j = tid + 64 * r;
      if (j < n) zs[j] = z[r] * inv;
    }
  }
  __syncthreads();
  if (tid == 0) {
    double wl = zs[n - 1];
    double sg = (wl >= 0.0) ? 1.0 : -1.0;
    double coef = 1.0 / (1.0 + fabs(wl));  // 2 / (2 + 2|wl|)
    zs[n - 1] = wl + sg;                   // zs now holds vhh
    scal[S_VTV] = 2.0 + 2.0 * fabs(wl);
    bc[0] = coef;
    double sc = 0.0;
    for (int i = 0; i < n; ++i) sc += zs[i] * tvsh[i];
    scal[S_SC] = sc * coef;
  }
  __syncthreads();
  const double coef = bc[0];
  {
    double acc = 0.0;
    for (int i = 0; i < n; ++i) acc += zs[i] * Mm[(size_t)i * DIM + tid];
    g[tid] = coef * acc;
  }
  for (int i = tid; i < n; i += 512) vhh[i] = zs[i];
}

// step-1: inverse iteration for the 321 kept tridiag eigenvectors (one thread each) + neighbor reorth
__global__ __launch_bounds__(512) void k_ii_multi(const double* __restrict__ d, const double* __restrict__ e,
                                                  const double* __restrict__ lam, int n, int keep_start,
                                                  double* __restrict__ Uk, double* __restrict__ cp) {
  const int tid = threadIdx.x, lane = tid & 63, wid = tid >> 6;
  __shared__ double redb[8];
  __shared__ double bc[1];
  if (tid < KEEP) {
    int j = tid;
    double lj = lam[keep_start + j];
    double me2 = 0.0;
    for (int i = 1; i < n; ++i) {
      double t = e[i - 1];
      me2 = fmax(me2, t * t);
    }
    double pivmin = fmax(me2 * 2.220446049250313e-16, 1e-280);
    unsigned s = 0x9E3779B9u * (unsigned)(j + 13);
    for (int i = 0; i < n; ++i) {
      s = s * 1664525u + 1013904223u;
      Uk[(size_t)i * KEEP + j] = 0.5 + (double)(s >> 8) * (1.0 / 16777216.0);
    }
    for (int it = 0; it < 3; ++it) {
      double den = d[0] - lj;
      if (fabs(den) < pivmin) den = (den < 0.0) ? -pivmin : pivmin;
      double cprev = e[0] / den;
      cp[0 * KEEP + j] = cprev;
      double zprev = Uk[0 * KEEP + j] / den;
      Uk[0 * KEEP + j] = zprev;
      for (int i = 1; i < n; ++i) {
        den = (d[i] - lj) - e[i - 1] * cprev;
        if (fabs(den) < pivmin) den = (den < 0.0) ? -pivmin : pivmin;
        double ci = (i < n - 1) ? e[i] / den : 0.0;
        cp[(size_t)i * KEEP + j] = ci;
        double zi = (Uk[(size_t)i * KEEP + j] - e[i - 1] * zprev) / den;
        Uk[(size_t)i * KEEP + j] = zi;
        zprev = zi;
        cprev = ci;
      }
      double zn = Uk[(size_t)(n - 1) * KEEP + j];
      for (int i = n - 2; i >= 0; --i) {
        zn = Uk[(size_t)i * KEEP + j] - cp[(size_t)i * KEEP + j] * zn;
        Uk[(size_t)i * KEEP + j] = zn;
      }
      double nn = 0;
      for (int i = 0; i < n; ++i) {
        double z = Uk[(size_t)i * KEEP + j];
        nn += z * z;
      }
      double inv = 1.0 / sqrt(fmax(nn, 1e-300));
      for (int i = 0; i < n; ++i) Uk[(size_t)i * KEEP + j] *= inv;
    }
  }
  __syncthreads();
  for (int jj = 1; jj < KEEP; ++jj) {
    double l1v = lam[keep_start + jj], l0v = lam[keep_start + jj - 1];
    bool close = (l1v - l0v) < 1e-7 * (fabs(l1v) + 1e-280);
    if (!close) continue;
    double p = 0;
    for (int i = tid; i < n; i += 512) p += Uk[(size_t)i * KEEP + jj] * Uk[(size_t)i * KEEP + jj - 1];
    p = wred(p);
    if (lane == 0) redb[wid] = p;
    __syncthreads();
    if (tid == 0) {
      double s2 = 0;
      for (int q = 0; q < 8; ++q) s2 += redb[q];
      bc[0] = s2;
    }
    __syncthreads();
    double dot = bc[0];
    for (int i = tid; i < n; i += 512) Uk[(size_t)i * KEEP + jj] -= dot * Uk[(size_t)i * KEEP + jj - 1];
    __syncthreads();
    p = 0;
    for (int i = tid; i < n; i += 512) {
      double z = Uk[(size_t)i * KEEP + jj];
      p += z * z;
    }
    p = wred(p);
    if (lane == 0) redb[wid] = p;
    __syncthreads();
    if (tid == 0) {
      double s2 = 0;
      for (int q = 0; q < 8; ++q) s2 += redb[q];
      bc[0] = 1.0 / sqrt(fmax(s2, 1e-300));
    }
    __syncthreads();
    double inv = bc[0];
    for (int i = tid; i < n; i += 512) Uk[(size_t)i * KEEP + jj] *= inv;
    __syncthreads();
  }
}

// apply stored Householder chain (Vrow, coalesced) to each kept eigenvector (one wave per column)
__global__ __launch_bounds__(64) void k_hhapply_multi(const double* __restrict__ Vrow, const double* __restrict__ tau,
                                                      int n, double* __restrict__ Uk) {
  const int j = blockIdx.x;
  const int lane = threadIdx.x;
  for (int k = n - 3; k >= 0; --k) {
    double tk = tau[k];
    if (tk == 0.0) continue;
    int m = n - 1 - k;
    const double* __restrict__ vr = Vrow + (size_t)k * n;
    double p = 0.0;
    for (int i = lane; i < m; i += 64) p += vr[i] * Uk[(size_t)(k + 1 + i) * KEEP + j];
    p = wred(p);
    p = __shfl(p, 0, 64);
    double tp = tk * p;
    for (int i = lane; i < m; i += 64) Uk[(size_t)(k + 1 + i) * KEEP + j] -= tp * vr[i];
  }
  double nn = 0.0;
  for (int i = lane; i < n; i += 64) {
    double z = Uk[(size_t)i * KEEP + j];
    nn += z * z;
  }
  nn = wred(nn);
  nn = __shfl(nn, 0, 64);
  double inv = 1.0 / sqrt(fmax(nn, 1e-300));
  for (int i = lane; i < n; i += 64) Uk[(size_t)i * KEEP + j] *= inv;
}

// C[MxN] = s * A^T·B  where A is Kd x M (lda), B is Kd x N (ldb), s = scal[S_SCALE]
__global__ __launch_bounds__(256) void k_gemm_tn(const double* __restrict__ A, const double* __restrict__ B,
                                                 double* __restrict__ C, int M, int N, int Kd, int lda, int ldb, int ldc,
                                                 const double* __restrict__ scal) {
  __shared__ double As[16][65];
  __shared__ double Bs[16][65];
  const int tid = threadIdx.x;
  const int tx = tid & 15, ty = tid >> 4;
  const int bi = blockIdx.y * 64, bj = blockIdx.x * 64;
  const int li = tid & 63, lq = tid >> 6;
  double acc[4][4] = {};
  for (int k0 = 0; k0 < Kd; k0 += 16) {
#pragma unroll
    for (int q = 0; q < 4; ++q) {
      int kk = lq + q * 4;
      int gk = k0 + kk;
      int gi = bi + li;
      int gj = bj + li;
      As[kk][li] = (gi < M && gk < Kd) ? A[(size_t)gk * lda + gi] : 0.0;
      Bs[kk][li] = (gj < N && gk < Kd) ? B[(size_t)gk * ldb + gj] : 0.0;
    }
    __syncthreads();
#pragma unroll
    for (int kk = 0; kk < 16; ++kk) {
      double a[4], bb[4];
#pragma unroll
      for (int u = 0; u < 4; ++u) a[u] = As[kk][ty * 4 + u];
#pragma unroll
      for (int v = 0; v < 4; ++v) bb[v] = Bs[kk][tx * 4 + v];
#pragma unroll
      for (int u = 0; u < 4; ++u)
#pragma unroll
        for (int v = 0; v < 4; ++v) acc[u][v] += a[u] * bb[v];
    }
    __syncthreads();
  }
  double s = scal[S_SCALE];
#pragma unroll
  for (int u = 0; u < 4; ++u) {
    int gi = bi + ty * 4 + u;
    if (gi >= M) continue;
#pragma unroll
    for (int v = 0; v < 4; ++v) {
      int gj = bj + tx * 4 + v;
      if (gj >= N) continue;
      C[(size_t)gi * ldc + gj] = s * acc[u][v];
    }
  }
}

// c_state = Uk^T tvec
__global__ __launch_bounds__(512) void k_gemv_tn(const double* __restrict__ Uk, const double* __restrict__ tvec,
                                                 double* __restrict__ cstv, int n) {
  int i = threadIdx.x;
  if (i < KEEP) {
    double acc = 0.0;
    for (int k = 0; k < n; ++k) acc += Uk[(size_t)k * KEEP + i] * tvec[k];
    cstv[i] = acc;
  }
}

// C_state = scale*(M - v g^T) rows 0..320 ;  c_state = (tvec - v*sc)[0..320]
__global__ __launch_bounds__(256) void k_hh_update(const double* __restrict__ Mm, const double* __restrict__ vhh,
                                                   const double* __restrict__ g, const double* __restrict__ scal,
                                                   const double* __restrict__ tvec, double* __restrict__ Cst,
                                                   double* __restrict__ cstv) {
  int idx = blockIdx.x * 256 + threadIdx.x;
  double scale = scal[S_SCALE];
  if (idx < KEEP * DIM) {
    int i = idx >> 9, j = idx & 511;
    Cst[(size_t)i * DIM + j] = scale * (Mm[(size_t)i * DIM + j] - vhh[i] * g[j]);
  }
  if (blockIdx.x == 0 && threadIdx.x < KEEP) {
    cstv[threadIdx.x] = tvec[threadIdx.x] - vhh[threadIdx.x] * scal[S_SC];
  }
}

// ---------------- host ----------------

extern "C" void kernel_launch(void* const* d_in, const int* in_sizes, int n_in, void* d_out, int out_size, void* d_ws,
                              size_t ws_size, hipStream_t stream) {
  (void)in_sizes;
  (void)n_in;
  (void)out_size;
  (void)ws_size;
  const float* x = (const float*)d_in[0];
  const float* W = (const float*)d_in[1];
  const float* b = (const float*)d_in[2];
  float* out = (float*)d_out;

  char* ws = (char*)d_ws;
  size_t off = 0;
  auto alloc = [&](size_t nelem) {
    size_t p = off;
    off += (nelem * 8 + 255) & ~(size_t)255;
    return (double*)(ws + p);
  };
  double* Wd = alloc(512 * 512);
  double* bd = alloc(512);
  double* mvec = alloc(512);
  double* Cst = alloc(512 * 512);
  double* cstv = alloc(520);
  double* tvec = alloc(520);
  double* Mm = alloc(513 * 512);
  // Union buffer: Gx (setup, dead after k_chol_mw) -> Aw (per step, dead after k_tridiag_mw)
  // -> cp scratch (step-1 k_ii_multi only, runs after tridiag). Lifetimes strictly disjoint.
  double* AwGx = alloc(513 * 513);
  double* Gx = AwGx;
  double* Aw = AwGx;
  double* zcp = AwGx;
  double* Vrow = alloc(513 * 513);
  double* dT = alloc(520);
  double* eT = alloc(520);
  double* tauT = alloc(520);
  double* lam = alloc(520);
  double* vhh = alloc(520);
  double* gv = alloc(520);
  double* scal = alloc(32);
  double* Uk = alloc(513 * 321);
  // multi-WG shared buffers (pvec/orow/vtpp double-buffered by iteration parity)
  double* pvec = alloc(1040);
  double* orow = alloc(1040);
  double* vtpp = alloc(64);
  unsigned* tflags = (unsigned*)alloc(512);  // 1024 uints, tridiag barrier
  unsigned* cflags = (unsigned*)alloc(512);  // 1024 uints, chol barrier
  // total ~12.0 MB

  // ---- setup ----
  k_cast<<<dim3((512 * 512 + 255) / 256), dim3(256), 0, stream>>>(W, b, Wd, bd, cflags);
  k_colsum<<<dim3(1), dim3(512), 0, stream>>>(x, mvec);
  k_xtx<<<dim3(8, 8), dim3(256), 0, stream>>>(x, Gx);
  k_chol_mw<<<dim3(TDG), dim3(256), 0, stream>>>(Gx, Cst, cflags);
  k_solvec0<<<dim3(1), dim3(64), 0, stream>>>(Cst, mvec, cstv);

  // ---- step 1 (r=512, n=513) ----
  {
    const int r = 512, n = 513;
    k_prep<<<dim3(1), dim3(512), 0, stream>>>(cstv, bd, r, tvec, Mm, scal, tflags);
    k_gemm_nt<<<dim3(8, 8), dim3(256), 0, stream>>>(Cst, Wd, Mm, r, 512, 512, 512, 512, 512, cstv, bd);
    k_syrk<<<dim3(45), dim3(256), 0, stream>>>(Mm, Aw, n, 512, 512, n);
    k_tridiag_mw<<<dim3(TDG), dim3(256), 0, stream>>>(Aw, n, dT, eT, tauT, Vrow, pvec, orow, vtpp, tflags);
    k_bisect_ms<<<dim3(n), dim3(64), 0, stream>>>(dT, eT, n, lam);
    k_specsum<<<dim3(1), dim3(64), 0, stream>>>(lam, n, n - KEEP, 0, out, scal);
    k_ii_multi<<<dim3(1), dim3(512), 0, stream>>>(dT, eT, lam, n, n - KEEP, Uk, zcp);
    k_hhapply_multi<<<dim3(KEEP), dim3(64), 0, stream>>>(Vrow, tauT, n, Uk);
    k_gemm_tn<<<dim3(8, 6), dim3(256), 0, stream>>>(Uk, Mm, Cst, KEEP, 512, n, KEEP, 512, 512, scal);
    k_gemv_tn<<<dim3(1), dim3(512), 0, stream>>>(Uk, tvec, cstv, n);
  }

  // ---- steps 2..30 (r=321, n=322) ----
  for (int t = 1; t < NSTEPS; ++t) {
    const int r = KEEP, n = KEEP + 1;
    k_prep<<<dim3(1), dim3(512), 0, stream>>>(cstv, bd, r, tvec, Mm, scal, tflags);
    k_gemm_nt<<<dim3(8, 6), dim3(256), 0, stream>>>(Cst, Wd, Mm, r, 512, 512, 512, 512, 512, cstv, bd);
    k_syrk<<<dim3(21), dim3(256), 0, stream>>>(Mm, Aw, n, 512, 512, n);
    k_tridiag_mw<<<dim3(TDG), dim3(256), 0, stream>>>(Aw, n, dT, eT, tauT, Vrow, pvec, orow, vtpp, tflags);
    k_bisect_ms<<<dim3(n), dim3(64), 0, stream>>>(dT, eT, n, lam);
    k_specsum<<<dim3(1), dim3(64), 0, stream>>>(lam, n, 1, t, out, scal);
    k_eigvec<<<dim3(1), dim3(512), 0, stream>>>(Vrow, n, dT, eT, tauT, lam, Mm, tvec, scal, vhh, gv);
    k_hh_update<<<dim3((KEEP * DIM + 255) / 256), dim3(256), 0, stream>>>(Mm, vhh, gv, scal, tvec, Cst, cstv);
  }
}